// Round 4
// baseline (234.242 us; speedup 1.0000x reference)
//
#include <hip/hip_runtime.h>
#include <cstdint>
#include <cstddef>

#define NPIX (512 * 512)
#define NMAPS 64
#define NPTS 300
#define CAP 2048           // per-map candidate region (64 bands x 32 slots)
#define SLOTS 32           // per-band-per-map candidate slots (E~9.7, 7 sigma)
#define LBUFSZ 64          // LDS staging per part
#define NWORDS 4096        // 262144 bits / 64
#define TARGET 700.0       // fallback rescan target
// Fixed keep-rate 20000/2^23: E~620 survivors/map.
// Compare raw threefry bits against MT<<9 (exactly equiv to score>=MT).
#define MT_BITS 0xFF63C000u  // (8388608-20000)<<9

__device__ __forceinline__ uint32_t umin32(uint32_t a, uint32_t b) {
  return a < b ? a : b;
}

// Portable rotate; r is always a compile-time constant in [6,29], clang
// lowers this to a single v_alignbit_b32 on gfx950.
__device__ __forceinline__ uint32_t rotl32(uint32_t x, int r) {
  return (x << r) | (x >> (32 - r));
}

// ---------------------------------------------------------------------------
// Threefry-2x32, 20 rounds (exactly JAX's formulation).
// Scalar version (K2 fallback + key derivation).
// ---------------------------------------------------------------------------
__device__ __forceinline__ void tf2x32(uint32_t k0, uint32_t k1,
                                       uint32_t x0, uint32_t x1,
                                       uint32_t& o0, uint32_t& o1) {
  uint32_t ks2 = k0 ^ k1 ^ 0x1BD11BDAu;
#define TFR(r) { x0 += x1; x1 = rotl32(x1, r); x1 ^= x0; }
  x0 += k0; x1 += k1;
  TFR(13) TFR(15) TFR(26) TFR(6)
  x0 += k1; x1 += ks2 + 1u;
  TFR(17) TFR(29) TFR(16) TFR(24)
  x0 += ks2; x1 += k0 + 2u;
  TFR(13) TFR(15) TFR(26) TFR(6)
  x0 += k0; x1 += k1 + 3u;
  TFR(17) TFR(29) TFR(16) TFR(24)
  x0 += k1; x1 += ks2 + 4u;
  TFR(13) TFR(15) TFR(26) TFR(6)
  x0 += ks2; x1 += k0 + 5u;
#undef TFR
  o0 = x0; o1 = x1;
}

// 4-pixel batched threefry: 4 manually interleaved chains (counter pb..pb+3).
// Guarantees 4-way ILP on the serial add->rotl->xor chain.
__device__ __forceinline__ void tf4(uint32_t k0, uint32_t k1, uint32_t pb,
                                    uint32_t& z0, uint32_t& z1, uint32_t& z2,
                                    uint32_t& z3) {
  const uint32_t ks2 = k0 ^ k1 ^ 0x1BD11BDAu;
  const uint32_t s = pb + k1;
  uint32_t a0 = k0, a1 = s;
  uint32_t b0 = k0, b1 = s + 1u;
  uint32_t c0 = k0, c1 = s + 2u;
  uint32_t d0 = k0, d1 = s + 3u;
#define R4(r)                                                         \
  a0 += a1; b0 += b1; c0 += c1; d0 += d1;                             \
  a1 = rotl32(a1, r); b1 = rotl32(b1, r);                             \
  c1 = rotl32(c1, r); d1 = rotl32(d1, r);                             \
  a1 ^= a0; b1 ^= b0; c1 ^= c0; d1 ^= d0;
#define K4(ka, kb)                                                    \
  a0 += (ka); b0 += (ka); c0 += (ka); d0 += (ka);                     \
  a1 += (kb); b1 += (kb); c1 += (kb); d1 += (kb);
  R4(13) R4(15) R4(26) R4(6)  K4(k1, ks2 + 1u)
  R4(17) R4(29) R4(16) R4(24) K4(ks2, k0 + 2u)
  R4(13) R4(15) R4(26) R4(6)  K4(k0, k1 + 3u)
  R4(17) R4(29) R4(16) R4(24) K4(k1, ks2 + 4u)
  R4(13) R4(15) R4(26) R4(6)  K4(ks2, k0 + 5u)
#undef R4
#undef K4
  z0 = a0 ^ a1; z1 = b0 ^ b1; z2 = c0 ^ c1; z3 = d0 ^ d1;
}

__device__ __forceinline__ uint32_t score23(uint32_t k0, uint32_t k1, uint32_t p) {
  uint32_t a, b;
  tf2x32(k0, k1, 0u, p, a, b);
  return (a ^ b) >> 9;
}

__device__ __forceinline__ void map_key(int m, uint32_t& k0, uint32_t& k1) {
  tf2x32(0u, 42u, 0u, (uint32_t)m, k0, k1);  // split(key(42),64)[m]
}

// DPP helper (validated ctrl constants; CTRL must be an ICE -> template).
template <int CTRL>
__device__ __forceinline__ uint32_t dpp_mov_u32(uint32_t x) {
  return (uint32_t)__builtin_amdgcn_update_dpp((int)x, (int)x, CTRL, 0xF, 0xF,
                                               false);
}

// DPP with old=0: invalid source lanes contribute 0 (for OR-reduce).
template <int CTRL>
__device__ __forceinline__ uint32_t dpp_or0(uint32_t x) {
  return (uint32_t)__builtin_amdgcn_update_dpp(0, (int)x, CTRL, 0xF, 0xF,
                                               false);
}

// ---------------------------------------------------------------------------
// K1 loads: 4 contiguous columns per lane via float4; sigmoid at load.
// ---------------------------------------------------------------------------
template <bool PRED, bool YIN>
__device__ __forceinline__ float4 ld4row(const float* __restrict__ src,
                                         int row, int X0) {
  if constexpr (!YIN) {
    if ((unsigned)row >= 512u) return make_float4(0.f, 0.f, 0.f, 0.f);
  }
  float4 v = *reinterpret_cast<const float4*>(src + (size_t)row * 512 + X0);
  if constexpr (PRED) {
    v.x = 1.f / (1.f + __expf(-v.x));
    v.y = 1.f / (1.f + __expf(-v.y));
    v.z = 1.f / (1.f + __expf(-v.z));
    v.w = 1.f / (1.f + __expf(-v.w));
  }
  return v;
}

template <bool PRED, bool YIN>
__device__ __forceinline__ float ldhrow(const float* __restrict__ src,
                                        int row, int hx, bool hact) {
  if (!hact) return 0.f;  // non-halo lanes: raw 0 (zero-pad semantics)
  if constexpr (!YIN) {
    if ((unsigned)row >= 512u) return 0.f;
  }
  float t = src[(size_t)row * 512 + hx];
  if constexpr (PRED) t = 1.f / (1.f + __expf(-t));
  return t;
}

__device__ __forceinline__ void push_surv(unsigned long long* lbuf,
                                          unsigned int* lcnt, uint32_t x,
                                          uint32_t p) {
  unsigned int pos = atomicAdd(lcnt, 1u);
  if (pos < LBUFSZ)
    lbuf[pos] = ((unsigned long long)(x >> 9) << 32) | (uint32_t)(~p);
}

// ---------------------------------------------------------------------------
// K1 part body: 4 rows x 256 cols (half width) of ONE map. Each wave runs
// this twice (pred part + mask part) -> perfect pred/mask load balance.
// 6 row-loads per 4 computed rows; rolling float4 regs fA..fD.
// ---------------------------------------------------------------------------
template <bool PRED, bool YIN>
__device__ __forceinline__ void part_body(
    const float* __restrict__ src, unsigned long long* __restrict__ bitmap,
    unsigned int* __restrict__ wcnts, unsigned long long* lbuf,
    unsigned int* lcnt, int m, int l, int h, int qq, uint32_t k0,
    uint32_t k1) {
  const int y0 = qq * 4;
  const int X0 = h * 256 + l * 4;
  const int hx = 256 - h;              // halo col: 256 (h=0) / 255 (h=1)
  const bool hact = h ? (l == 0) : (l == 63);
  const int lr = l & 15;

  float4 fA = ld4row<PRED, YIN>(src, y0 - 1, X0);
  float4 fB = ld4row<PRED, YIN>(src, y0 + 0, X0);
  float4 fC = ld4row<PRED, YIN>(src, y0 + 1, X0);
  float4 fD = ld4row<PRED, YIN>(src, y0 + 2, X0);
  float sA = ldhrow<PRED, YIN>(src, y0 - 1, hx, hact);
  float sB = ldhrow<PRED, YIN>(src, y0 + 0, hx, hact);
  float sC = ldhrow<PRED, YIN>(src, y0 + 1, hx, hact);
  float sD = ldhrow<PRED, YIN>(src, y0 + 2, hx, hact);

  unsigned int cnt = 0;
  unsigned long long* __restrict__ bm2 =
      bitmap + (size_t)m * NWORDS + (size_t)y0 * 8 + (h * 4 + (l >> 4));
  uint32_t pbase = (uint32_t)(y0 * 512 + X0);

#define ROWQ(RA, RB, RC, SA, SB, SC, II)                                      \
  do {                                                                        \
    float t0 = RA.x + 2.f * RB.x + RC.x, t1 = RA.y + 2.f * RB.y + RC.y;       \
    float t2 = RA.z + 2.f * RB.z + RC.z, t3 = RA.w + 2.f * RB.w + RC.w;       \
    float u0 = RC.x - RA.x, u1 = RC.y - RA.y;                                 \
    float u2 = RC.z - RA.z, u3 = RC.w - RA.w;                                 \
    float th = SA + 2.f * SB + SC, uh = SC - SA;                              \
    float tU = __shfl_up(t3, 1), uU = __shfl_up(u3, 1);                       \
    float tD = __shfl_down(t0, 1), uD = __shfl_down(u0, 1);                   \
    if (l == 0) { tU = th; uU = uh; }                                         \
    if (l == 63) { tD = th; uD = uh; }                                        \
    float ex0 = t1 - tU, ex1 = t2 - t0, ex2 = t3 - t1, ex3 = tD - t2;         \
    float ey0 = uU + 2.f * u0 + u1, ey1 = u0 + 2.f * u1 + u2;                 \
    float ey2 = u1 + 2.f * u2 + u3, ey3 = u2 + 2.f * u3 + uD;                 \
    uint32_t nib = (ex0 * ex0 + ey0 * ey0 > 0.25f ? 1u : 0u) |                \
                   (ex1 * ex1 + ey1 * ey1 > 0.25f ? 2u : 0u) |                \
                   (ex2 * ex2 + ey2 * ey2 > 0.25f ? 4u : 0u) |                \
                   (ex3 * ex3 + ey3 * ey3 > 0.25f ? 8u : 0u);                 \
    uint32_t z0, z1, z2, z3;                                                  \
    tf4(k0, k1, pbase, z0, z1, z2, z3);                                       \
    uint32_t qm = (z0 >= MT_BITS ? 1u : 0u) | (z1 >= MT_BITS ? 2u : 0u) |     \
                  (z2 >= MT_BITS ? 4u : 0u) | (z3 >= MT_BITS ? 8u : 0u);      \
    uint32_t sv = nib & qm;                                                   \
    if (sv) {                                                                 \
      if (sv & 1u) push_surv(lbuf, lcnt, z0, pbase);                          \
      if (sv & 2u) push_surv(lbuf, lcnt, z1, pbase + 1u);                     \
      if (sv & 4u) push_surv(lbuf, lcnt, z2, pbase + 2u);                     \
      if (sv & 8u) push_surv(lbuf, lcnt, z3, pbase + 3u);                     \
    }                                                                         \
    unsigned long long full = (unsigned long long)nib << (4 * lr);            \
    uint32_t wlo = (uint32_t)full, whi = (uint32_t)(full >> 32);              \
    wlo |= dpp_or0<0x111>(wlo); whi |= dpp_or0<0x111>(whi);                   \
    wlo |= dpp_or0<0x112>(wlo); whi |= dpp_or0<0x112>(whi);                   \
    wlo |= dpp_or0<0x114>(wlo); whi |= dpp_or0<0x114>(whi);                   \
    wlo |= dpp_or0<0x118>(wlo); whi |= dpp_or0<0x118>(whi);                   \
    if (lr == 15) {                                                           \
      unsigned long long word = ((unsigned long long)whi << 32) | wlo;        \
      bm2[(II) * 8] = word;                                                   \
      cnt += (unsigned int)__popcll(word);                                    \
    }                                                                         \
    pbase += 512u;                                                            \
  } while (0)

  ROWQ(fA, fB, fC, sA, sB, sC, 0);
  fA = ld4row<PRED, YIN>(src, y0 + 3, X0);
  sA = ldhrow<PRED, YIN>(src, y0 + 3, hx, hact);
  ROWQ(fB, fC, fD, sB, sC, sD, 1);
  fB = ld4row<PRED, YIN>(src, y0 + 4, X0);
  sB = ldhrow<PRED, YIN>(src, y0 + 4, hx, hact);
  ROWQ(fC, fD, fA, sC, sD, sA, 2);
  ROWQ(fD, fA, fB, sD, sA, sB, 3);
#undef ROWQ

  // unit total = sum of the 4 tail-lane partials (lanes 15/31/47/63).
  cnt += __shfl_xor(cnt, 16);
  cnt += __shfl_xor(cnt, 32);
  if (l == 15) wcnts[m * 256 + 2 * qq + h] = cnt;
}

// ---------------------------------------------------------------------------
// K1: fused Sobel+threefry+collect, pred/mask balanced. 2048 blocks (1D):
// block b -> sample s = b>>6, band j = b&63 (rows [8j, 8j+8)). Each of the
// 4 waves: h = v&1, qq = 2j + (v>>1); does 4 pred rows THEN 4 mask rows.
// Every block has identical cost -> no pred-tail.
// ---------------------------------------------------------------------------
__global__ __launch_bounds__(256) void edge_collect_kernel(
    const float* __restrict__ mo, const float* __restrict__ lb,
    unsigned long long* __restrict__ bitmap, unsigned int* __restrict__ wcnts,
    unsigned long long* __restrict__ cand, unsigned int* __restrict__ bcnt,
    float* __restrict__ out) {
  const int b = blockIdx.x;
  const int s = b >> 6;        // sample [0,32)
  const int j = b & 63;        // 8-row band [0,64)
  const int v = threadIdx.x >> 6;
  const int l = threadIdx.x & 63;
  const int h = v & 1;
  const int qq = 2 * j + (v >> 1);  // row-quad [0,128)
  const int mA = 2 * s;        // pred map (model_output)
  const int mB = 2 * s + 1;    // mask map (labels)
  const float* __restrict__ srcP = mo + (size_t)s * NPIX;
  const float* __restrict__ srcM = lb + (size_t)s * NPIX;

  if (b == 0 && threadIdx.x == 0) out[0] = 0.f;

  __shared__ unsigned long long lbufP[LBUFSZ], lbufM[LBUFSZ];
  __shared__ unsigned int lcntP, lcntM;
  if (threadIdx.x == 0) { lcntP = 0; lcntM = 0; }
  __syncthreads();

  uint32_t ka0, ka1, kb0, kb1;
  map_key(mA, ka0, ka1);
  map_key(mB, kb0, kb1);
  ka0 = (uint32_t)__builtin_amdgcn_readfirstlane((int)ka0);
  ka1 = (uint32_t)__builtin_amdgcn_readfirstlane((int)ka1);
  kb0 = (uint32_t)__builtin_amdgcn_readfirstlane((int)kb0);
  kb1 = (uint32_t)__builtin_amdgcn_readfirstlane((int)kb1);

  const bool yin = (qq != 0) && (qq != 127);
  if (yin) {
    part_body<true, true>(srcP, bitmap, wcnts, lbufP, &lcntP, mA, l, h, qq, ka0, ka1);
    part_body<false, true>(srcM, bitmap, wcnts, lbufM, &lcntM, mB, l, h, qq, kb0, kb1);
  } else {
    part_body<true, false>(srcP, bitmap, wcnts, lbufP, &lcntP, mA, l, h, qq, ka0, ka1);
    part_body<false, false>(srcM, bitmap, wcnts, lbufM, &lcntM, mB, l, h, qq, kb0, kb1);
  }

  __syncthreads();
  const unsigned int tP = lcntP, tM = lcntM;
  const unsigned int ccP = tP < SLOTS ? tP : SLOTS;
  const unsigned int ccM = tM < SLOTS ? tM : SLOTS;
  for (unsigned int i = threadIdx.x; i < ccP; i += 256)
    cand[(size_t)mA * CAP + j * SLOTS + i] = lbufP[i];
  for (unsigned int i = threadIdx.x; i < ccM; i += 256)
    cand[(size_t)mB * CAP + j * SLOTS + i] = lbufM[i];
  if (threadIdx.x == 0) {
    bcnt[mA * 64 + j] = tP;
    bcnt[mB * 64 + j] = tM;
  }
}

// block-level N = sum of the 256 per-unit counts.
__device__ __forceinline__ void reduce_N(const unsigned int* __restrict__ wcnts,
                                         int m, int tid, unsigned int* sN) {
  if (tid < 64) {
    const unsigned int* w = wcnts + m * 256;
    unsigned int v = w[tid] + w[tid + 64] + w[tid + 128] + w[tid + 192];
#pragma unroll
    for (int off = 32; off > 0; off >>= 1) v += __shfl_xor(v, off, 64);
    if (tid == 0) *sN = v;
  }
}

// ---------------------------------------------------------------------------
// K2: compact per-band slots -> radix-SELECT top-`need` set. Fallback exact
// bitmap rescan on overflow/shortfall (correctness unconditional).
// ---------------------------------------------------------------------------
__global__ __launch_bounds__(256) void select_kernel(
    const unsigned long long* __restrict__ bitmap,
    const unsigned int* __restrict__ wcnts,
    const unsigned long long* __restrict__ cand,
    const unsigned int* __restrict__ bcnt,
    uint32_t* __restrict__ pts, unsigned int* __restrict__ nsel) {
  const int m = blockIdx.x;
  const int tid = threadIdx.x;
  __shared__ unsigned long long buf[CAP];
  __shared__ unsigned int hist[256];
  __shared__ unsigned int scnt64[64];
  __shared__ unsigned int sbase[65];
  __shared__ unsigned int s_tot, s_cnt, s_b, s_rank, sN, s_ovf;

  reduce_N(wcnts, m, tid, &sN);
  if (tid < 64) scnt64[tid] = bcnt[m * 64 + tid];
  __syncthreads();
  const unsigned int N = sN;
  if (N == 0) { if (tid == 0) nsel[m] = 0; return; }
  const unsigned int need = N < NPTS ? N : NPTS;

  if (tid == 0) {
    unsigned int s = 0, ovf = 0;
    for (int i = 0; i < 64; ++i) {
      sbase[i] = s;
      unsigned int cg = scnt64[i];
      if (cg > SLOTS) ovf = 1;
      s += cg < SLOTS ? cg : SLOTS;
    }
    sbase[64] = s;
    s_ovf = ovf;
  }
  __syncthreads();

  unsigned int c;
  if (!s_ovf && sbase[64] >= need) {
    c = sbase[64];
    const int g = tid >> 2, j0 = tid & 3;  // 64 groups x 4 threads
    const unsigned int cg = scnt64[g] < SLOTS ? scnt64[g] : SLOTS;
    for (unsigned int i = j0; i < cg; i += 4)
      buf[sbase[g] + i] = cand[(size_t)m * CAP + g * SLOTS + i];
    __syncthreads();
  } else {
    // fallback: exact iterative rescan of the bitmap
    uint32_t k0, k1;
    map_key(m, k0, k1);
    const unsigned long long* __restrict__ wmap = bitmap + (size_t)m * NWORDS;
    unsigned int mt = 0, cnt = 0;
    double target = TARGET;
    for (int iter = 0; iter < 16; ++iter) {
      mt = ((double)N > target)
               ? (unsigned int)(8388608.0 * (1.0 - target / (double)N))
               : 0u;
      if (tid == 0) s_tot = 0;
      __syncthreads();
      unsigned int lc = 0;
      for (int w = tid; w < NWORDS; w += 256) {
        unsigned long long word = wmap[w];
        while (word) {
          int bpos = __builtin_ctzll(word);
          word &= word - 1;
          uint32_t p = ((uint32_t)w << 6) + (uint32_t)bpos;
          lc += (score23(k0, k1, p) >= mt) ? 1u : 0u;
        }
      }
      if (lc) atomicAdd(&s_tot, lc);
      __syncthreads();
      cnt = s_tot;
      __syncthreads();
      if (cnt >= need && cnt <= CAP) break;
      if (cnt < need) target *= 3.0; else target *= 0.5;
    }
    if (tid == 0) s_cnt = 0;
    __syncthreads();
    for (int w = tid; w < NWORDS; w += 256) {
      unsigned long long word = wmap[w];
      while (word) {
        int bpos = __builtin_ctzll(word);
        word &= word - 1;
        uint32_t p = ((uint32_t)w << 6) + (uint32_t)bpos;
        uint32_t sc = score23(k0, k1, p);
        if (sc >= mt) {
          unsigned int pos = atomicAdd(&s_cnt, 1u);
          if (pos < CAP)
            buf[pos] = ((unsigned long long)sc << 32) | (uint32_t)(~p);
        }
      }
    }
    __syncthreads();
    c = s_cnt < CAP ? s_cnt : CAP;
    __syncthreads();
  }

  unsigned long long T = 0ull;
  if (c > need) {
    unsigned int rank = need;
    unsigned long long prefix = 0ull;
    for (int sh = 48; sh >= 0; sh -= 8) {
      hist[tid] = 0;
      __syncthreads();
      for (unsigned int i = tid; i < c; i += 256) {
        unsigned long long k = buf[i];
        if ((k >> (sh + 8)) == (prefix >> (sh + 8)))
          atomicAdd(&hist[(unsigned int)(k >> sh) & 255u], 1u);
      }
      __syncthreads();
      if (tid < 64) {
        unsigned int h0 = hist[4 * tid], h1 = hist[4 * tid + 1];
        unsigned int h2 = hist[4 * tid + 2], h3 = hist[4 * tid + 3];
        unsigned int gsum = h0 + h1 + h2 + h3;
        unsigned int s = gsum;
#pragma unroll
        for (int off = 1; off < 64; off <<= 1) {
          unsigned int o = __shfl_down(s, off, 64);
          s += (tid + off < 64) ? o : 0u;
        }
        unsigned int above = s - gsum;  // strictly higher digits
        unsigned int S3 = above, S2 = S3 + h3, S1 = S2 + h2, S0 = S1 + h1;
        if (S3 < rank && rank <= S3 + h3) { s_b = 4 * tid + 3; s_rank = rank - S3; }
        if (S2 < rank && rank <= S2 + h2) { s_b = 4 * tid + 2; s_rank = rank - S2; }
        if (S1 < rank && rank <= S1 + h1) { s_b = 4 * tid + 1; s_rank = rank - S1; }
        if (S0 < rank && rank <= S0 + h0) { s_b = 4 * tid + 0; s_rank = rank - S0; }
      }
      __syncthreads();
      prefix |= ((unsigned long long)s_b) << sh;
      rank = s_rank;
    }
    T = prefix;  // exact need-th largest key
  }

  if (tid == 0) s_cnt = 0;
  __syncthreads();
  for (unsigned int i = tid; i < c; i += 256) {
    unsigned long long k = buf[i];
    if (k >= T) {
      unsigned int pos = atomicAdd(&s_cnt, 1u);
      if (pos < NPTS) {
        uint32_t p = ~(uint32_t)k;
        pts[(size_t)m * NPTS + pos] = ((p >> 9) << 16) | (p & 511u);
      }
    }
  }
  __syncthreads();
  if (tid == 0) nsel[m] = s_cnt < need ? s_cnt : need;
}

// ---------------------------------------------------------------------------
// K3: Prim MST + fused finalize. Serial-latency-optimized:
//  - reduce = 4 DPP row_shr + 4 parallel readlanes + scalar min tree
//    (replaces 6-DPP butterfly + readlane: 2 fewer serial cross-lane hops)
//  - pj = 5 parallel readlanes + uniform select (replaces 4 chained cndmask)
//  - best/j/ko/lo/utp are uniform -> SALU, off the VALU critical path
// Integer math identical to the r3 kernel (absmax 0 preserved).
// ---------------------------------------------------------------------------
__global__ __launch_bounds__(128, 1) void mst_kernel(
    const uint32_t* __restrict__ pts, const unsigned int* __restrict__ nsel,
    float* __restrict__ out) {
  const int wv = threadIdx.x >> 6;  // 0 = pred, 1 = mask
  const int m = blockIdx.x * 2 + wv;
  const int l = threadIdx.x & 63;
  const int n = (int)nsel[m];
  __shared__ float stp[2];

  uint32_t utp = 0;
  if (n > 1) {
    uint32_t pk[5], key[5];
#pragma unroll
    for (int k = 0; k < 5; ++k) {
      int id = k * 64 + l;
      pk[k] = (id < n) ? pts[(size_t)m * NPTS + id] : 0u;
    }
    const uint32_t p0 = (uint32_t)__builtin_amdgcn_readlane((int)pk[0], 0);
    const int x0 = (int)(p0 >> 16), y0 = (int)(p0 & 0xFFFFu);
#pragma unroll
    for (int k = 0; k < 5; ++k) {
      int id = k * 64 + l;
      if (id > 0 && id < n) {
        int dx = (int)(pk[k] >> 16) - x0, dy = (int)(pk[k] & 0xFFFFu) - y0;
        key[k] = ((uint32_t)(__mul24(dx, dx) + __mul24(dy, dy)) << 9) |
                 (uint32_t)id;
      } else {
        key[k] = 0xFFFFFFFFu;
      }
    }

    for (int it = 0; it < n - 1; ++it) {
      // local 5-min (depth 3), then 4-step row_shr reduce: row mins land in
      // lanes 15/31/47/63 (row_shr does not cross 16-lane row boundaries).
      uint32_t v = umin32(umin32(umin32(key[0], key[1]),
                                 umin32(key[2], key[3])), key[4]);
      v = umin32(v, dpp_mov_u32<0x111>(v));  // row_shr:1
      v = umin32(v, dpp_mov_u32<0x112>(v));  // row_shr:2
      v = umin32(v, dpp_mov_u32<0x114>(v));  // row_shr:4
      v = umin32(v, dpp_mov_u32<0x118>(v));  // row_shr:8
      const uint32_t r0 = (uint32_t)__builtin_amdgcn_readlane((int)v, 15);
      const uint32_t r1 = (uint32_t)__builtin_amdgcn_readlane((int)v, 31);
      const uint32_t r2 = (uint32_t)__builtin_amdgcn_readlane((int)v, 47);
      const uint32_t r3 = (uint32_t)__builtin_amdgcn_readlane((int)v, 63);
      const uint32_t best = umin32(umin32(r0, r1), umin32(r2, r3));  // SALU
      utp += best >> 9;  // exact: sum < 2^31 (uniform, SALU)
      const int j = (int)(best & 511u);
      const int ko = j >> 6, lo = j & 63;
      // 5 independent readlanes + uniform select tree (SALU).
      const uint32_t q0 = (uint32_t)__builtin_amdgcn_readlane((int)pk[0], lo);
      const uint32_t q1 = (uint32_t)__builtin_amdgcn_readlane((int)pk[1], lo);
      const uint32_t q2 = (uint32_t)__builtin_amdgcn_readlane((int)pk[2], lo);
      const uint32_t q3 = (uint32_t)__builtin_amdgcn_readlane((int)pk[3], lo);
      const uint32_t q4 = (uint32_t)__builtin_amdgcn_readlane((int)pk[4], lo);
      const uint32_t pj = ko == 0 ? q0
                          : ko == 1 ? q1
                          : ko == 2 ? q2
                          : ko == 3 ? q3 : q4;
      const int jx = (int)(pj >> 16), jy = (int)(pj & 0xFFFFu);
#pragma unroll
      for (int k = 0; k < 5; ++k) {
        int dx = (int)(pk[k] >> 16) - jx, dy = (int)(pk[k] & 0xFFFFu) - jy;
        uint32_t nk = ((uint32_t)(__mul24(dx, dx) + __mul24(dy, dy)) << 9) |
                      (uint32_t)(k * 64 + l);
        uint32_t upd =
            (key[k] == 0xFFFFFFFFu) ? 0xFFFFFFFFu : umin32(key[k], nk);
        key[k] = (k == ko && l == lo) ? 0xFFFFFFFFu : upd;
      }
    }
  }
  if (l == 0) stp[wv] = (float)utp;
  __syncthreads();
  if (threadIdx.x == 0)
    atomicAdd(out, 1e-5f * fabsf(stp[1] - stp[0]) / 32.f);
}

// ---------------------------------------------------------------------------
extern "C" void kernel_launch(void* const* d_in, const int* in_sizes, int n_in,
                              void* d_out, int out_size, void* d_ws,
                              size_t ws_size, hipStream_t stream) {
  const float* mo = (const float*)d_in[0];
  const float* lb = (const float*)d_in[1];
  float* out = (float*)d_out;
  char* ws = (char*)d_ws;

  // ws layout (~3.30 MB):
  unsigned long long* bitmap = (unsigned long long*)ws;            // 2 MB
  unsigned long long* cand = (unsigned long long*)(ws + 2097152);  // 1 MB
  unsigned int* wcnts = (unsigned int*)(ws + 3145728);             // 64 KB
  unsigned int* bcnt  = (unsigned int*)(ws + 3211264);             // 16 KB
  unsigned int* nsel  = (unsigned int*)(ws + 3227648);             // 256 B
  uint32_t* pts       = (uint32_t*)(ws + 3227904);                 // 75 KB

  edge_collect_kernel<<<2048, 256, 0, stream>>>(mo, lb, bitmap, wcnts,
                                                cand, bcnt, out);
  select_kernel<<<NMAPS, 256, 0, stream>>>(bitmap, wcnts, cand, bcnt, pts,
                                           nsel);
  mst_kernel<<<32, 128, 0, stream>>>(pts, nsel, out);
}

// Round 5
// 227.921 us; speedup vs baseline: 1.0277x; 1.0277x over previous
//
#include <hip/hip_runtime.h>
#include <cstdint>
#include <cstddef>

#define NPIX (512 * 512)
#define NMAPS 64
#define NPTS 300
#define CAP 2048           // per-map candidate region (64 bands x 32 slots)
#define SLOTS 32           // per-band-per-map candidate slots (E~9.7, 7 sigma)
#define LBUFSZ 64          // LDS staging per part
#define NWORDS 4096        // 262144 bits / 64
#define TARGET 700.0       // fallback rescan target
// Fixed keep-rate 20000/2^23: E~620 survivors/map.
// Compare raw threefry bits against MT<<9 (exactly equiv to score>=MT).
#define MT_BITS 0xFF63C000u  // (8388608-20000)<<9

__device__ __forceinline__ uint32_t umin32(uint32_t a, uint32_t b) {
  return a < b ? a : b;
}

// Portable rotate; r is always a compile-time constant in [6,29], clang
// lowers this to a single v_alignbit_b32 on gfx950.
__device__ __forceinline__ uint32_t rotl32(uint32_t x, int r) {
  return (x << r) | (x >> (32 - r));
}

// ---------------------------------------------------------------------------
// Threefry-2x32, 20 rounds (exactly JAX's formulation).
// Scalar version (K2 fallback + key derivation).
// ---------------------------------------------------------------------------
__device__ __forceinline__ void tf2x32(uint32_t k0, uint32_t k1,
                                       uint32_t x0, uint32_t x1,
                                       uint32_t& o0, uint32_t& o1) {
  uint32_t ks2 = k0 ^ k1 ^ 0x1BD11BDAu;
#define TFR(r) { x0 += x1; x1 = rotl32(x1, r); x1 ^= x0; }
  x0 += k0; x1 += k1;
  TFR(13) TFR(15) TFR(26) TFR(6)
  x0 += k1; x1 += ks2 + 1u;
  TFR(17) TFR(29) TFR(16) TFR(24)
  x0 += ks2; x1 += k0 + 2u;
  TFR(13) TFR(15) TFR(26) TFR(6)
  x0 += k0; x1 += k1 + 3u;
  TFR(17) TFR(29) TFR(16) TFR(24)
  x0 += k1; x1 += ks2 + 4u;
  TFR(13) TFR(15) TFR(26) TFR(6)
  x0 += ks2; x1 += k0 + 5u;
#undef TFR
  o0 = x0; o1 = x1;
}

// 4-pixel batched threefry: 4 manually interleaved chains (counter pb..pb+3).
// Guarantees 4-way ILP on the serial add->rotl->xor chain.
__device__ __forceinline__ void tf4(uint32_t k0, uint32_t k1, uint32_t pb,
                                    uint32_t& z0, uint32_t& z1, uint32_t& z2,
                                    uint32_t& z3) {
  const uint32_t ks2 = k0 ^ k1 ^ 0x1BD11BDAu;
  const uint32_t s = pb + k1;
  uint32_t a0 = k0, a1 = s;
  uint32_t b0 = k0, b1 = s + 1u;
  uint32_t c0 = k0, c1 = s + 2u;
  uint32_t d0 = k0, d1 = s + 3u;
#define R4(r)                                                         \
  a0 += a1; b0 += b1; c0 += c1; d0 += d1;                             \
  a1 = rotl32(a1, r); b1 = rotl32(b1, r);                             \
  c1 = rotl32(c1, r); d1 = rotl32(d1, r);                             \
  a1 ^= a0; b1 ^= b0; c1 ^= c0; d1 ^= d0;
#define K4(ka, kb)                                                    \
  a0 += (ka); b0 += (ka); c0 += (ka); d0 += (ka);                     \
  a1 += (kb); b1 += (kb); c1 += (kb); d1 += (kb);
  R4(13) R4(15) R4(26) R4(6)  K4(k1, ks2 + 1u)
  R4(17) R4(29) R4(16) R4(24) K4(ks2, k0 + 2u)
  R4(13) R4(15) R4(26) R4(6)  K4(k0, k1 + 3u)
  R4(17) R4(29) R4(16) R4(24) K4(k1, ks2 + 4u)
  R4(13) R4(15) R4(26) R4(6)  K4(ks2, k0 + 5u)
#undef R4
#undef K4
  z0 = a0 ^ a1; z1 = b0 ^ b1; z2 = c0 ^ c1; z3 = d0 ^ d1;
}

__device__ __forceinline__ uint32_t score23(uint32_t k0, uint32_t k1, uint32_t p) {
  uint32_t a, b;
  tf2x32(k0, k1, 0u, p, a, b);
  return (a ^ b) >> 9;
}

__device__ __forceinline__ void map_key(int m, uint32_t& k0, uint32_t& k1) {
  tf2x32(0u, 42u, 0u, (uint32_t)m, k0, k1);  // split(key(42),64)[m]
}

// DPP helper (validated ctrl constants; CTRL must be an ICE -> template).
template <int CTRL>
__device__ __forceinline__ uint32_t dpp_mov_u32(uint32_t x) {
  return (uint32_t)__builtin_amdgcn_update_dpp((int)x, (int)x, CTRL, 0xF, 0xF,
                                               false);
}

// DPP with old=0: invalid source lanes contribute 0 (for OR-reduce).
template <int CTRL>
__device__ __forceinline__ uint32_t dpp_or0(uint32_t x) {
  return (uint32_t)__builtin_amdgcn_update_dpp(0, (int)x, CTRL, 0xF, 0xF,
                                               false);
}

// ---------------------------------------------------------------------------
// K1 loads: 4 contiguous columns per lane via float4; sigmoid at load.
// ---------------------------------------------------------------------------
template <bool PRED, bool YIN>
__device__ __forceinline__ float4 ld4row(const float* __restrict__ src,
                                         int row, int X0) {
  if constexpr (!YIN) {
    if ((unsigned)row >= 512u) return make_float4(0.f, 0.f, 0.f, 0.f);
  }
  float4 v = *reinterpret_cast<const float4*>(src + (size_t)row * 512 + X0);
  if constexpr (PRED) {
    v.x = 1.f / (1.f + __expf(-v.x));
    v.y = 1.f / (1.f + __expf(-v.y));
    v.z = 1.f / (1.f + __expf(-v.z));
    v.w = 1.f / (1.f + __expf(-v.w));
  }
  return v;
}

template <bool PRED, bool YIN>
__device__ __forceinline__ float ldhrow(const float* __restrict__ src,
                                        int row, int hx, bool hact) {
  if (!hact) return 0.f;  // non-halo lanes: raw 0 (zero-pad semantics)
  if constexpr (!YIN) {
    if ((unsigned)row >= 512u) return 0.f;
  }
  float t = src[(size_t)row * 512 + hx];
  if constexpr (PRED) t = 1.f / (1.f + __expf(-t));
  return t;
}

__device__ __forceinline__ void push_surv(unsigned long long* lbuf,
                                          unsigned int* lcnt, uint32_t x,
                                          uint32_t p) {
  unsigned int pos = atomicAdd(lcnt, 1u);
  if (pos < LBUFSZ)
    lbuf[pos] = ((unsigned long long)(x >> 9) << 32) | (uint32_t)(~p);
}

// ---------------------------------------------------------------------------
// K1 part body: 4 rows x 256 cols (half width) of ONE map. Each wave runs
// this twice (pred part + mask part) -> perfect pred/mask load balance.
// 6 row-loads per 4 computed rows; rolling float4 regs fA..fD.
// ---------------------------------------------------------------------------
template <bool PRED, bool YIN>
__device__ __forceinline__ void part_body(
    const float* __restrict__ src, unsigned long long* __restrict__ bitmap,
    unsigned int* __restrict__ wcnts, unsigned long long* lbuf,
    unsigned int* lcnt, int m, int l, int h, int qq, uint32_t k0,
    uint32_t k1) {
  const int y0 = qq * 4;
  const int X0 = h * 256 + l * 4;
  const int hx = 256 - h;              // halo col: 256 (h=0) / 255 (h=1)
  const bool hact = h ? (l == 0) : (l == 63);
  const int lr = l & 15;

  float4 fA = ld4row<PRED, YIN>(src, y0 - 1, X0);
  float4 fB = ld4row<PRED, YIN>(src, y0 + 0, X0);
  float4 fC = ld4row<PRED, YIN>(src, y0 + 1, X0);
  float4 fD = ld4row<PRED, YIN>(src, y0 + 2, X0);
  float sA = ldhrow<PRED, YIN>(src, y0 - 1, hx, hact);
  float sB = ldhrow<PRED, YIN>(src, y0 + 0, hx, hact);
  float sC = ldhrow<PRED, YIN>(src, y0 + 1, hx, hact);
  float sD = ldhrow<PRED, YIN>(src, y0 + 2, hx, hact);

  unsigned int cnt = 0;
  unsigned long long* __restrict__ bm2 =
      bitmap + (size_t)m * NWORDS + (size_t)y0 * 8 + (h * 4 + (l >> 4));
  uint32_t pbase = (uint32_t)(y0 * 512 + X0);

#define ROWQ(RA, RB, RC, SA, SB, SC, II)                                      \
  do {                                                                        \
    float t0 = RA.x + 2.f * RB.x + RC.x, t1 = RA.y + 2.f * RB.y + RC.y;       \
    float t2 = RA.z + 2.f * RB.z + RC.z, t3 = RA.w + 2.f * RB.w + RC.w;       \
    float u0 = RC.x - RA.x, u1 = RC.y - RA.y;                                 \
    float u2 = RC.z - RA.z, u3 = RC.w - RA.w;                                 \
    float th = SA + 2.f * SB + SC, uh = SC - SA;                              \
    float tU = __shfl_up(t3, 1), uU = __shfl_up(u3, 1);                       \
    float tD = __shfl_down(t0, 1), uD = __shfl_down(u0, 1);                   \
    if (l == 0) { tU = th; uU = uh; }                                         \
    if (l == 63) { tD = th; uD = uh; }                                        \
    float ex0 = t1 - tU, ex1 = t2 - t0, ex2 = t3 - t1, ex3 = tD - t2;         \
    float ey0 = uU + 2.f * u0 + u1, ey1 = u0 + 2.f * u1 + u2;                 \
    float ey2 = u1 + 2.f * u2 + u3, ey3 = u2 + 2.f * u3 + uD;                 \
    uint32_t nib = (ex0 * ex0 + ey0 * ey0 > 0.25f ? 1u : 0u) |                \
                   (ex1 * ex1 + ey1 * ey1 > 0.25f ? 2u : 0u) |                \
                   (ex2 * ex2 + ey2 * ey2 > 0.25f ? 4u : 0u) |                \
                   (ex3 * ex3 + ey3 * ey3 > 0.25f ? 8u : 0u);                 \
    uint32_t z0, z1, z2, z3;                                                  \
    tf4(k0, k1, pbase, z0, z1, z2, z3);                                       \
    uint32_t qm = (z0 >= MT_BITS ? 1u : 0u) | (z1 >= MT_BITS ? 2u : 0u) |     \
                  (z2 >= MT_BITS ? 4u : 0u) | (z3 >= MT_BITS ? 8u : 0u);      \
    uint32_t sv = nib & qm;                                                   \
    if (sv) {                                                                 \
      if (sv & 1u) push_surv(lbuf, lcnt, z0, pbase);                          \
      if (sv & 2u) push_surv(lbuf, lcnt, z1, pbase + 1u);                     \
      if (sv & 4u) push_surv(lbuf, lcnt, z2, pbase + 2u);                     \
      if (sv & 8u) push_surv(lbuf, lcnt, z3, pbase + 3u);                     \
    }                                                                         \
    unsigned long long full = (unsigned long long)nib << (4 * lr);            \
    uint32_t wlo = (uint32_t)full, whi = (uint32_t)(full >> 32);              \
    wlo |= dpp_or0<0x111>(wlo); whi |= dpp_or0<0x111>(whi);                   \
    wlo |= dpp_or0<0x112>(wlo); whi |= dpp_or0<0x112>(whi);                   \
    wlo |= dpp_or0<0x114>(wlo); whi |= dpp_or0<0x114>(whi);                   \
    wlo |= dpp_or0<0x118>(wlo); whi |= dpp_or0<0x118>(whi);                   \
    if (lr == 15) {                                                           \
      unsigned long long word = ((unsigned long long)whi << 32) | wlo;        \
      bm2[(II) * 8] = word;                                                   \
      cnt += (unsigned int)__popcll(word);                                    \
    }                                                                         \
    pbase += 512u;                                                            \
  } while (0)

  ROWQ(fA, fB, fC, sA, sB, sC, 0);
  fA = ld4row<PRED, YIN>(src, y0 + 3, X0);
  sA = ldhrow<PRED, YIN>(src, y0 + 3, hx, hact);
  ROWQ(fB, fC, fD, sB, sC, sD, 1);
  fB = ld4row<PRED, YIN>(src, y0 + 4, X0);
  sB = ldhrow<PRED, YIN>(src, y0 + 4, hx, hact);
  ROWQ(fC, fD, fA, sC, sD, sA, 2);
  ROWQ(fD, fA, fB, sD, sA, sB, 3);
#undef ROWQ

  // unit total = sum of the 4 tail-lane partials (lanes 15/31/47/63).
  cnt += __shfl_xor(cnt, 16);
  cnt += __shfl_xor(cnt, 32);
  if (l == 15) wcnts[m * 256 + 2 * qq + h] = cnt;
}

// ---------------------------------------------------------------------------
// K1: fused Sobel+threefry+collect, pred/mask balanced. 2048 blocks (1D):
// block b -> sample s = b>>6, band j = b&63 (rows [8j, 8j+8)). Each of the
// 4 waves: h = v&1, qq = 2j + (v>>1); does 4 pred rows THEN 4 mask rows.
// Every block has identical cost -> no pred-tail.
// ---------------------------------------------------------------------------
__global__ __launch_bounds__(256) void edge_collect_kernel(
    const float* __restrict__ mo, const float* __restrict__ lb,
    unsigned long long* __restrict__ bitmap, unsigned int* __restrict__ wcnts,
    unsigned long long* __restrict__ cand, unsigned int* __restrict__ bcnt,
    float* __restrict__ out) {
  const int b = blockIdx.x;
  const int s = b >> 6;        // sample [0,32)
  const int j = b & 63;        // 8-row band [0,64)
  const int v = threadIdx.x >> 6;
  const int l = threadIdx.x & 63;
  const int h = v & 1;
  const int qq = 2 * j + (v >> 1);  // row-quad [0,128)
  const int mA = 2 * s;        // pred map (model_output)
  const int mB = 2 * s + 1;    // mask map (labels)
  const float* __restrict__ srcP = mo + (size_t)s * NPIX;
  const float* __restrict__ srcM = lb + (size_t)s * NPIX;

  if (b == 0 && threadIdx.x == 0) out[0] = 0.f;

  __shared__ unsigned long long lbufP[LBUFSZ], lbufM[LBUFSZ];
  __shared__ unsigned int lcntP, lcntM;
  if (threadIdx.x == 0) { lcntP = 0; lcntM = 0; }
  __syncthreads();

  uint32_t ka0, ka1, kb0, kb1;
  map_key(mA, ka0, ka1);
  map_key(mB, kb0, kb1);
  ka0 = (uint32_t)__builtin_amdgcn_readfirstlane((int)ka0);
  ka1 = (uint32_t)__builtin_amdgcn_readfirstlane((int)ka1);
  kb0 = (uint32_t)__builtin_amdgcn_readfirstlane((int)kb0);
  kb1 = (uint32_t)__builtin_amdgcn_readfirstlane((int)kb1);

  const bool yin = (qq != 0) && (qq != 127);
  if (yin) {
    part_body<true, true>(srcP, bitmap, wcnts, lbufP, &lcntP, mA, l, h, qq, ka0, ka1);
    part_body<false, true>(srcM, bitmap, wcnts, lbufM, &lcntM, mB, l, h, qq, kb0, kb1);
  } else {
    part_body<true, false>(srcP, bitmap, wcnts, lbufP, &lcntP, mA, l, h, qq, ka0, ka1);
    part_body<false, false>(srcM, bitmap, wcnts, lbufM, &lcntM, mB, l, h, qq, kb0, kb1);
  }

  __syncthreads();
  const unsigned int tP = lcntP, tM = lcntM;
  const unsigned int ccP = tP < SLOTS ? tP : SLOTS;
  const unsigned int ccM = tM < SLOTS ? tM : SLOTS;
  for (unsigned int i = threadIdx.x; i < ccP; i += 256)
    cand[(size_t)mA * CAP + j * SLOTS + i] = lbufP[i];
  for (unsigned int i = threadIdx.x; i < ccM; i += 256)
    cand[(size_t)mB * CAP + j * SLOTS + i] = lbufM[i];
  if (threadIdx.x == 0) {
    bcnt[mA * 64 + j] = tP;
    bcnt[mB * 64 + j] = tM;
  }
}

// block-level N = sum of the 256 per-unit counts.
__device__ __forceinline__ void reduce_N(const unsigned int* __restrict__ wcnts,
                                         int m, int tid, unsigned int* sN) {
  if (tid < 64) {
    const unsigned int* w = wcnts + m * 256;
    unsigned int v = w[tid] + w[tid + 64] + w[tid + 128] + w[tid + 192];
#pragma unroll
    for (int off = 32; off > 0; off >>= 1) v += __shfl_xor(v, off, 64);
    if (tid == 0) *sN = v;
  }
}

// ---------------------------------------------------------------------------
// K2: compact per-band slots -> radix-SELECT top-`need` set. Fallback exact
// bitmap rescan on overflow/shortfall (correctness unconditional).
// ---------------------------------------------------------------------------
__global__ __launch_bounds__(256) void select_kernel(
    const unsigned long long* __restrict__ bitmap,
    const unsigned int* __restrict__ wcnts,
    const unsigned long long* __restrict__ cand,
    const unsigned int* __restrict__ bcnt,
    uint32_t* __restrict__ pts, unsigned int* __restrict__ nsel) {
  const int m = blockIdx.x;
  const int tid = threadIdx.x;
  __shared__ unsigned long long buf[CAP];
  __shared__ unsigned int hist[256];
  __shared__ unsigned int scnt64[64];
  __shared__ unsigned int sbase[65];
  __shared__ unsigned int s_tot, s_cnt, s_b, s_rank, sN, s_ovf;

  reduce_N(wcnts, m, tid, &sN);
  if (tid < 64) scnt64[tid] = bcnt[m * 64 + tid];
  __syncthreads();
  const unsigned int N = sN;
  if (N == 0) { if (tid == 0) nsel[m] = 0; return; }
  const unsigned int need = N < NPTS ? N : NPTS;

  if (tid == 0) {
    unsigned int s = 0, ovf = 0;
    for (int i = 0; i < 64; ++i) {
      sbase[i] = s;
      unsigned int cg = scnt64[i];
      if (cg > SLOTS) ovf = 1;
      s += cg < SLOTS ? cg : SLOTS;
    }
    sbase[64] = s;
    s_ovf = ovf;
  }
  __syncthreads();

  unsigned int c;
  if (!s_ovf && sbase[64] >= need) {
    c = sbase[64];
    const int g = tid >> 2, j0 = tid & 3;  // 64 groups x 4 threads
    const unsigned int cg = scnt64[g] < SLOTS ? scnt64[g] : SLOTS;
    for (unsigned int i = j0; i < cg; i += 4)
      buf[sbase[g] + i] = cand[(size_t)m * CAP + g * SLOTS + i];
    __syncthreads();
  } else {
    // fallback: exact iterative rescan of the bitmap
    uint32_t k0, k1;
    map_key(m, k0, k1);
    const unsigned long long* __restrict__ wmap = bitmap + (size_t)m * NWORDS;
    unsigned int mt = 0, cnt = 0;
    double target = TARGET;
    for (int iter = 0; iter < 16; ++iter) {
      mt = ((double)N > target)
               ? (unsigned int)(8388608.0 * (1.0 - target / (double)N))
               : 0u;
      if (tid == 0) s_tot = 0;
      __syncthreads();
      unsigned int lc = 0;
      for (int w = tid; w < NWORDS; w += 256) {
        unsigned long long word = wmap[w];
        while (word) {
          int bpos = __builtin_ctzll(word);
          word &= word - 1;
          uint32_t p = ((uint32_t)w << 6) + (uint32_t)bpos;
          lc += (score23(k0, k1, p) >= mt) ? 1u : 0u;
        }
      }
      if (lc) atomicAdd(&s_tot, lc);
      __syncthreads();
      cnt = s_tot;
      __syncthreads();
      if (cnt >= need && cnt <= CAP) break;
      if (cnt < need) target *= 3.0; else target *= 0.5;
    }
    if (tid == 0) s_cnt = 0;
    __syncthreads();
    for (int w = tid; w < NWORDS; w += 256) {
      unsigned long long word = wmap[w];
      while (word) {
        int bpos = __builtin_ctzll(word);
        word &= word - 1;
        uint32_t p = ((uint32_t)w << 6) + (uint32_t)bpos;
        uint32_t sc = score23(k0, k1, p);
        if (sc >= mt) {
          unsigned int pos = atomicAdd(&s_cnt, 1u);
          if (pos < CAP)
            buf[pos] = ((unsigned long long)sc << 32) | (uint32_t)(~p);
        }
      }
    }
    __syncthreads();
    c = s_cnt < CAP ? s_cnt : CAP;
    __syncthreads();
  }

  unsigned long long T = 0ull;
  if (c > need) {
    unsigned int rank = need;
    unsigned long long prefix = 0ull;
    for (int sh = 48; sh >= 0; sh -= 8) {
      hist[tid] = 0;
      __syncthreads();
      for (unsigned int i = tid; i < c; i += 256) {
        unsigned long long k = buf[i];
        if ((k >> (sh + 8)) == (prefix >> (sh + 8)))
          atomicAdd(&hist[(unsigned int)(k >> sh) & 255u], 1u);
      }
      __syncthreads();
      if (tid < 64) {
        unsigned int h0 = hist[4 * tid], h1 = hist[4 * tid + 1];
        unsigned int h2 = hist[4 * tid + 2], h3 = hist[4 * tid + 3];
        unsigned int gsum = h0 + h1 + h2 + h3;
        unsigned int s = gsum;
#pragma unroll
        for (int off = 1; off < 64; off <<= 1) {
          unsigned int o = __shfl_down(s, off, 64);
          s += (tid + off < 64) ? o : 0u;
        }
        unsigned int above = s - gsum;  // strictly higher digits
        unsigned int S3 = above, S2 = S3 + h3, S1 = S2 + h2, S0 = S1 + h1;
        if (S3 < rank && rank <= S3 + h3) { s_b = 4 * tid + 3; s_rank = rank - S3; }
        if (S2 < rank && rank <= S2 + h2) { s_b = 4 * tid + 2; s_rank = rank - S2; }
        if (S1 < rank && rank <= S1 + h1) { s_b = 4 * tid + 1; s_rank = rank - S1; }
        if (S0 < rank && rank <= S0 + h0) { s_b = 4 * tid + 0; s_rank = rank - S0; }
      }
      __syncthreads();
      prefix |= ((unsigned long long)s_b) << sh;
      rank = s_rank;
    }
    T = prefix;  // exact need-th largest key
  }

  if (tid == 0) s_cnt = 0;
  __syncthreads();
  for (unsigned int i = tid; i < c; i += 256) {
    unsigned long long k = buf[i];
    if (k >= T) {
      unsigned int pos = atomicAdd(&s_cnt, 1u);
      if (pos < NPTS) {
        uint32_t p = ~(uint32_t)k;
        pts[(size_t)m * NPTS + pos] = ((p >> 9) << 16) | (p & 511u);
      }
    }
  }
  __syncthreads();
  if (tid == 0) nsel[m] = s_cnt < need ? s_cnt : need;
}

// ---------------------------------------------------------------------------
// K3: Prim MST + fused finalize. All-VGPR serial chain (r4 lesson: readlane
// VALU->SALU hazards cost ~18cy each; keep the chain in one domain):
//  - cross-lane min: 4 DPP (quad_perm xor1/xor2, half/row mirror) +
//    __shfl_xor 16/32 -> EVERY lane holds the uniform min (no readlane).
//  - pj: depth-3 cndmask tree (vector ko) + one __shfl (ds_bpermute).
//  - utp/j/ko/lo stay vector (uniform-valued); lane 0 writes at the end.
// Integer math identical to r3 (min is order-invariant) -> absmax 0.
// ---------------------------------------------------------------------------
__global__ __launch_bounds__(128, 1) void mst_kernel(
    const uint32_t* __restrict__ pts, const unsigned int* __restrict__ nsel,
    float* __restrict__ out) {
  const int wv = threadIdx.x >> 6;  // 0 = pred, 1 = mask
  const int m = blockIdx.x * 2 + wv;
  const int l = threadIdx.x & 63;
  const int n = (int)nsel[m];
  __shared__ float stp[2];

  uint32_t utp = 0;
  if (n > 1) {
    uint32_t pk[5], key[5];
#pragma unroll
    for (int k = 0; k < 5; ++k) {
      int id = k * 64 + l;
      pk[k] = (id < n) ? pts[(size_t)m * NPTS + id] : 0u;
    }
    const uint32_t p0 = (uint32_t)__builtin_amdgcn_readlane((int)pk[0], 0);
    const int x0 = (int)(p0 >> 16), y0 = (int)(p0 & 0xFFFFu);
#pragma unroll
    for (int k = 0; k < 5; ++k) {
      int id = k * 64 + l;
      if (id > 0 && id < n) {
        int dx = (int)(pk[k] >> 16) - x0, dy = (int)(pk[k] & 0xFFFFu) - y0;
        key[k] = ((uint32_t)(__mul24(dx, dx) + __mul24(dy, dy)) << 9) |
                 (uint32_t)id;
      } else {
        key[k] = 0xFFFFFFFFu;
      }
    }

    for (int it = 0; it < n - 1; ++it) {
      // local 5-min (depth 3), then all-lanes reduction entirely in the
      // vector domain: 4 DPP mins + 2 shfl_xor mins.
      uint32_t v = umin32(umin32(umin32(key[0], key[1]),
                                 umin32(key[2], key[3])), key[4]);
      v = umin32(v, dpp_mov_u32<0xB1>(v));   // quad_perm [1,0,3,2]  (xor 1)
      v = umin32(v, dpp_mov_u32<0x4E>(v));   // quad_perm [2,3,0,1]  (xor 2)
      v = umin32(v, dpp_mov_u32<0x141>(v));  // row_half_mirror      (8-grp)
      v = umin32(v, dpp_mov_u32<0x140>(v));  // row_mirror           (16-row)
      v = umin32(v, (uint32_t)__shfl_xor((int)v, 16));
      const uint32_t best = umin32(v, (uint32_t)__shfl_xor((int)v, 32));
      // best is uniform across all 64 lanes (VGPR domain, no readlane).
      utp += best >> 9;  // exact: sum < 2^31
      const uint32_t j = best & 511u;
      const uint32_t ko = j >> 6;
      const uint32_t lo = j & 63u;
      // depth-3 select tree (vector ko), then one bpermute broadcast.
      uint32_t c01 = (ko == 1u) ? pk[1] : pk[0];
      uint32_t c23 = (ko == 3u) ? pk[3] : pk[2];
      uint32_t c03 = (ko >= 2u) ? c23 : c01;
      uint32_t cp = (ko == 4u) ? pk[4] : c03;
      const uint32_t pj = (uint32_t)__shfl((int)cp, (int)lo);
      const int jx = (int)(pj >> 16), jy = (int)(pj & 0xFFFFu);
#pragma unroll
      for (int k = 0; k < 5; ++k) {
        int dx = (int)(pk[k] >> 16) - jx, dy = (int)(pk[k] & 0xFFFFu) - jy;
        uint32_t nk = ((uint32_t)(__mul24(dx, dx) + __mul24(dy, dy)) << 9) |
                      (uint32_t)(k * 64 + l);
        uint32_t upd =
            (key[k] == 0xFFFFFFFFu) ? 0xFFFFFFFFu : umin32(key[k], nk);
        key[k] = ((uint32_t)k == ko && (uint32_t)l == lo) ? 0xFFFFFFFFu : upd;
      }
    }
  }
  if (l == 0) stp[wv] = (float)utp;
  __syncthreads();
  if (threadIdx.x == 0)
    atomicAdd(out, 1e-5f * fabsf(stp[1] - stp[0]) / 32.f);
}

// ---------------------------------------------------------------------------
extern "C" void kernel_launch(void* const* d_in, const int* in_sizes, int n_in,
                              void* d_out, int out_size, void* d_ws,
                              size_t ws_size, hipStream_t stream) {
  const float* mo = (const float*)d_in[0];
  const float* lb = (const float*)d_in[1];
  float* out = (float*)d_out;
  char* ws = (char*)d_ws;

  // ws layout (~3.30 MB):
  unsigned long long* bitmap = (unsigned long long*)ws;            // 2 MB
  unsigned long long* cand = (unsigned long long*)(ws + 2097152);  // 1 MB
  unsigned int* wcnts = (unsigned int*)(ws + 3145728);             // 64 KB
  unsigned int* bcnt  = (unsigned int*)(ws + 3211264);             // 16 KB
  unsigned int* nsel  = (unsigned int*)(ws + 3227648);             // 256 B
  uint32_t* pts       = (uint32_t*)(ws + 3227904);                 // 75 KB

  edge_collect_kernel<<<2048, 256, 0, stream>>>(mo, lb, bitmap, wcnts,
                                                cand, bcnt, out);
  select_kernel<<<NMAPS, 256, 0, stream>>>(bitmap, wcnts, cand, bcnt, pts,
                                           nsel);
  mst_kernel<<<32, 128, 0, stream>>>(pts, nsel, out);
}

// Round 6
// 219.638 us; speedup vs baseline: 1.0665x; 1.0377x over previous
//
#include <hip/hip_runtime.h>
#include <cstdint>
#include <cstddef>

#define NPIX (512 * 512)
#define NMAPS 64
#define NPTS 300
#define CAP 2048           // per-map candidate region (64 bands x 32 slots)
#define SLOTS 32           // per-band-per-map candidate slots (E~9.7, 7 sigma)
#define LBUFSZ 64          // LDS staging per part
#define NWORDS 4096        // 262144 bits / 64
#define TARGET 700.0       // fallback rescan target
// Fixed keep-rate 20000/2^23: E~620 survivors/map.
// Compare raw threefry bits against MT<<9 (exactly equiv to score>=MT).
#define MT_BITS 0xFF63C000u  // (8388608-20000)<<9

__device__ __forceinline__ uint32_t umin32(uint32_t a, uint32_t b) {
  return a < b ? a : b;
}

// Portable rotate; r is always a compile-time constant in [6,29], clang
// lowers this to a single v_alignbit_b32 on gfx950.
__device__ __forceinline__ uint32_t rotl32(uint32_t x, int r) {
  return (x << r) | (x >> (32 - r));
}

// ---------------------------------------------------------------------------
// Threefry-2x32, 20 rounds (exactly JAX's formulation).
// Scalar version (K2 fallback + key derivation).
// ---------------------------------------------------------------------------
__device__ __forceinline__ void tf2x32(uint32_t k0, uint32_t k1,
                                       uint32_t x0, uint32_t x1,
                                       uint32_t& o0, uint32_t& o1) {
  uint32_t ks2 = k0 ^ k1 ^ 0x1BD11BDAu;
#define TFR(r) { x0 += x1; x1 = rotl32(x1, r); x1 ^= x0; }
  x0 += k0; x1 += k1;
  TFR(13) TFR(15) TFR(26) TFR(6)
  x0 += k1; x1 += ks2 + 1u;
  TFR(17) TFR(29) TFR(16) TFR(24)
  x0 += ks2; x1 += k0 + 2u;
  TFR(13) TFR(15) TFR(26) TFR(6)
  x0 += k0; x1 += k1 + 3u;
  TFR(17) TFR(29) TFR(16) TFR(24)
  x0 += k1; x1 += ks2 + 4u;
  TFR(13) TFR(15) TFR(26) TFR(6)
  x0 += ks2; x1 += k0 + 5u;
#undef TFR
  o0 = x0; o1 = x1;
}

// 4-pixel batched threefry: 4 manually interleaved chains (counter pb..pb+3).
// Guarantees 4-way ILP on the serial add->rotl->xor chain.
__device__ __forceinline__ void tf4(uint32_t k0, uint32_t k1, uint32_t pb,
                                    uint32_t& z0, uint32_t& z1, uint32_t& z2,
                                    uint32_t& z3) {
  const uint32_t ks2 = k0 ^ k1 ^ 0x1BD11BDAu;
  const uint32_t s = pb + k1;
  uint32_t a0 = k0, a1 = s;
  uint32_t b0 = k0, b1 = s + 1u;
  uint32_t c0 = k0, c1 = s + 2u;
  uint32_t d0 = k0, d1 = s + 3u;
#define R4(r)                                                         \
  a0 += a1; b0 += b1; c0 += c1; d0 += d1;                             \
  a1 = rotl32(a1, r); b1 = rotl32(b1, r);                             \
  c1 = rotl32(c1, r); d1 = rotl32(d1, r);                             \
  a1 ^= a0; b1 ^= b0; c1 ^= c0; d1 ^= d0;
#define K4(ka, kb)                                                    \
  a0 += (ka); b0 += (ka); c0 += (ka); d0 += (ka);                     \
  a1 += (kb); b1 += (kb); c1 += (kb); d1 += (kb);
  R4(13) R4(15) R4(26) R4(6)  K4(k1, ks2 + 1u)
  R4(17) R4(29) R4(16) R4(24) K4(ks2, k0 + 2u)
  R4(13) R4(15) R4(26) R4(6)  K4(k0, k1 + 3u)
  R4(17) R4(29) R4(16) R4(24) K4(k1, ks2 + 4u)
  R4(13) R4(15) R4(26) R4(6)  K4(ks2, k0 + 5u)
#undef R4
#undef K4
  z0 = a0 ^ a1; z1 = b0 ^ b1; z2 = c0 ^ c1; z3 = d0 ^ d1;
}

__device__ __forceinline__ uint32_t score23(uint32_t k0, uint32_t k1, uint32_t p) {
  uint32_t a, b;
  tf2x32(k0, k1, 0u, p, a, b);
  return (a ^ b) >> 9;
}

__device__ __forceinline__ void map_key(int m, uint32_t& k0, uint32_t& k1) {
  tf2x32(0u, 42u, 0u, (uint32_t)m, k0, k1);  // split(key(42),64)[m]
}

// DPP helper (validated ctrl constants; CTRL must be an ICE -> template).
template <int CTRL>
__device__ __forceinline__ uint32_t dpp_mov_u32(uint32_t x) {
  return (uint32_t)__builtin_amdgcn_update_dpp((int)x, (int)x, CTRL, 0xF, 0xF,
                                               false);
}

// DPP with old=0: invalid source lanes contribute 0 (for OR-reduce).
template <int CTRL>
__device__ __forceinline__ uint32_t dpp_or0(uint32_t x) {
  return (uint32_t)__builtin_amdgcn_update_dpp(0, (int)x, CTRL, 0xF, 0xF,
                                               false);
}

// ---------------------------------------------------------------------------
// K1 loads: 4 contiguous columns per lane via float4; sigmoid at load.
// ---------------------------------------------------------------------------
template <bool PRED, bool YIN>
__device__ __forceinline__ float4 ld4row(const float* __restrict__ src,
                                         int row, int X0) {
  if constexpr (!YIN) {
    if ((unsigned)row >= 512u) return make_float4(0.f, 0.f, 0.f, 0.f);
  }
  float4 v = *reinterpret_cast<const float4*>(src + (size_t)row * 512 + X0);
  if constexpr (PRED) {
    v.x = 1.f / (1.f + __expf(-v.x));
    v.y = 1.f / (1.f + __expf(-v.y));
    v.z = 1.f / (1.f + __expf(-v.z));
    v.w = 1.f / (1.f + __expf(-v.w));
  }
  return v;
}

template <bool PRED, bool YIN>
__device__ __forceinline__ float ldhrow(const float* __restrict__ src,
                                        int row, int hx, bool hact) {
  if (!hact) return 0.f;  // non-halo lanes: raw 0 (zero-pad semantics)
  if constexpr (!YIN) {
    if ((unsigned)row >= 512u) return 0.f;
  }
  float t = src[(size_t)row * 512 + hx];
  if constexpr (PRED) t = 1.f / (1.f + __expf(-t));
  return t;
}

__device__ __forceinline__ void push_surv(unsigned long long* lbuf,
                                          unsigned int* lcnt, uint32_t x,
                                          uint32_t p) {
  unsigned int pos = atomicAdd(lcnt, 1u);
  if (pos < LBUFSZ)
    lbuf[pos] = ((unsigned long long)(x >> 9) << 32) | (uint32_t)(~p);
}

// ---------------------------------------------------------------------------
// K1 part body: 4 rows x 256 cols (half width) of ONE map. Each wave runs
// this twice (pred part + mask part) -> perfect pred/mask load balance.
// 6 row-loads per 4 computed rows; rolling float4 regs fA..fD.
// ---------------------------------------------------------------------------
template <bool PRED, bool YIN>
__device__ __forceinline__ void part_body(
    const float* __restrict__ src, unsigned long long* __restrict__ bitmap,
    unsigned int* __restrict__ wcnts, unsigned long long* lbuf,
    unsigned int* lcnt, int m, int l, int h, int qq, uint32_t k0,
    uint32_t k1) {
  const int y0 = qq * 4;
  const int X0 = h * 256 + l * 4;
  const int hx = 256 - h;              // halo col: 256 (h=0) / 255 (h=1)
  const bool hact = h ? (l == 0) : (l == 63);
  const int lr = l & 15;

  float4 fA = ld4row<PRED, YIN>(src, y0 - 1, X0);
  float4 fB = ld4row<PRED, YIN>(src, y0 + 0, X0);
  float4 fC = ld4row<PRED, YIN>(src, y0 + 1, X0);
  float4 fD = ld4row<PRED, YIN>(src, y0 + 2, X0);
  float sA = ldhrow<PRED, YIN>(src, y0 - 1, hx, hact);
  float sB = ldhrow<PRED, YIN>(src, y0 + 0, hx, hact);
  float sC = ldhrow<PRED, YIN>(src, y0 + 1, hx, hact);
  float sD = ldhrow<PRED, YIN>(src, y0 + 2, hx, hact);

  unsigned int cnt = 0;
  unsigned long long* __restrict__ bm2 =
      bitmap + (size_t)m * NWORDS + (size_t)y0 * 8 + (h * 4 + (l >> 4));
  uint32_t pbase = (uint32_t)(y0 * 512 + X0);

#define ROWQ(RA, RB, RC, SA, SB, SC, II)                                      \
  do {                                                                        \
    float t0 = RA.x + 2.f * RB.x + RC.x, t1 = RA.y + 2.f * RB.y + RC.y;       \
    float t2 = RA.z + 2.f * RB.z + RC.z, t3 = RA.w + 2.f * RB.w + RC.w;       \
    float u0 = RC.x - RA.x, u1 = RC.y - RA.y;                                 \
    float u2 = RC.z - RA.z, u3 = RC.w - RA.w;                                 \
    float th = SA + 2.f * SB + SC, uh = SC - SA;                              \
    float tU = __shfl_up(t3, 1), uU = __shfl_up(u3, 1);                       \
    float tD = __shfl_down(t0, 1), uD = __shfl_down(u0, 1);                   \
    if (l == 0) { tU = th; uU = uh; }                                         \
    if (l == 63) { tD = th; uD = uh; }                                        \
    float ex0 = t1 - tU, ex1 = t2 - t0, ex2 = t3 - t1, ex3 = tD - t2;         \
    float ey0 = uU + 2.f * u0 + u1, ey1 = u0 + 2.f * u1 + u2;                 \
    float ey2 = u1 + 2.f * u2 + u3, ey3 = u2 + 2.f * u3 + uD;                 \
    uint32_t nib = (ex0 * ex0 + ey0 * ey0 > 0.25f ? 1u : 0u) |                \
                   (ex1 * ex1 + ey1 * ey1 > 0.25f ? 2u : 0u) |                \
                   (ex2 * ex2 + ey2 * ey2 > 0.25f ? 4u : 0u) |                \
                   (ex3 * ex3 + ey3 * ey3 > 0.25f ? 8u : 0u);                 \
    uint32_t z0, z1, z2, z3;                                                  \
    tf4(k0, k1, pbase, z0, z1, z2, z3);                                       \
    uint32_t qm = (z0 >= MT_BITS ? 1u : 0u) | (z1 >= MT_BITS ? 2u : 0u) |     \
                  (z2 >= MT_BITS ? 4u : 0u) | (z3 >= MT_BITS ? 8u : 0u);      \
    uint32_t sv = nib & qm;                                                   \
    if (sv) {                                                                 \
      if (sv & 1u) push_surv(lbuf, lcnt, z0, pbase);                          \
      if (sv & 2u) push_surv(lbuf, lcnt, z1, pbase + 1u);                     \
      if (sv & 4u) push_surv(lbuf, lcnt, z2, pbase + 2u);                     \
      if (sv & 8u) push_surv(lbuf, lcnt, z3, pbase + 3u);                     \
    }                                                                         \
    unsigned long long full = (unsigned long long)nib << (4 * lr);            \
    uint32_t wlo = (uint32_t)full, whi = (uint32_t)(full >> 32);              \
    wlo |= dpp_or0<0x111>(wlo); whi |= dpp_or0<0x111>(whi);                   \
    wlo |= dpp_or0<0x112>(wlo); whi |= dpp_or0<0x112>(whi);                   \
    wlo |= dpp_or0<0x114>(wlo); whi |= dpp_or0<0x114>(whi);                   \
    wlo |= dpp_or0<0x118>(wlo); whi |= dpp_or0<0x118>(whi);                   \
    if (lr == 15) {                                                           \
      unsigned long long word = ((unsigned long long)whi << 32) | wlo;        \
      bm2[(II) * 8] = word;                                                   \
      cnt += (unsigned int)__popcll(word);                                    \
    }                                                                         \
    pbase += 512u;                                                            \
  } while (0)

  ROWQ(fA, fB, fC, sA, sB, sC, 0);
  fA = ld4row<PRED, YIN>(src, y0 + 3, X0);
  sA = ldhrow<PRED, YIN>(src, y0 + 3, hx, hact);
  ROWQ(fB, fC, fD, sB, sC, sD, 1);
  fB = ld4row<PRED, YIN>(src, y0 + 4, X0);
  sB = ldhrow<PRED, YIN>(src, y0 + 4, hx, hact);
  ROWQ(fC, fD, fA, sC, sD, sA, 2);
  ROWQ(fD, fA, fB, sD, sA, sB, 3);
#undef ROWQ

  // unit total = sum of the 4 tail-lane partials (lanes 15/31/47/63).
  cnt += __shfl_xor(cnt, 16);
  cnt += __shfl_xor(cnt, 32);
  if (l == 15) wcnts[m * 256 + 2 * qq + h] = cnt;
}

// ---------------------------------------------------------------------------
// K1: fused Sobel+threefry+collect, pred/mask balanced. 2048 blocks (1D):
// block b -> sample s = b>>6, band j = b&63 (rows [8j, 8j+8)). Each of the
// 4 waves: h = v&1, qq = 2j + (v>>1); does 4 pred rows THEN 4 mask rows.
// Every block has identical cost -> no pred-tail.
// ---------------------------------------------------------------------------
__global__ __launch_bounds__(256) void edge_collect_kernel(
    const float* __restrict__ mo, const float* __restrict__ lb,
    unsigned long long* __restrict__ bitmap, unsigned int* __restrict__ wcnts,
    unsigned long long* __restrict__ cand, unsigned int* __restrict__ bcnt,
    float* __restrict__ out) {
  const int b = blockIdx.x;
  const int s = b >> 6;        // sample [0,32)
  const int j = b & 63;        // 8-row band [0,64)
  const int v = threadIdx.x >> 6;
  const int l = threadIdx.x & 63;
  const int h = v & 1;
  const int qq = 2 * j + (v >> 1);  // row-quad [0,128)
  const int mA = 2 * s;        // pred map (model_output)
  const int mB = 2 * s + 1;    // mask map (labels)
  const float* __restrict__ srcP = mo + (size_t)s * NPIX;
  const float* __restrict__ srcM = lb + (size_t)s * NPIX;

  if (b == 0 && threadIdx.x == 0) out[0] = 0.f;

  __shared__ unsigned long long lbufP[LBUFSZ], lbufM[LBUFSZ];
  __shared__ unsigned int lcntP, lcntM;
  if (threadIdx.x == 0) { lcntP = 0; lcntM = 0; }
  __syncthreads();

  uint32_t ka0, ka1, kb0, kb1;
  map_key(mA, ka0, ka1);
  map_key(mB, kb0, kb1);
  ka0 = (uint32_t)__builtin_amdgcn_readfirstlane((int)ka0);
  ka1 = (uint32_t)__builtin_amdgcn_readfirstlane((int)ka1);
  kb0 = (uint32_t)__builtin_amdgcn_readfirstlane((int)kb0);
  kb1 = (uint32_t)__builtin_amdgcn_readfirstlane((int)kb1);

  const bool yin = (qq != 0) && (qq != 127);
  if (yin) {
    part_body<true, true>(srcP, bitmap, wcnts, lbufP, &lcntP, mA, l, h, qq, ka0, ka1);
    part_body<false, true>(srcM, bitmap, wcnts, lbufM, &lcntM, mB, l, h, qq, kb0, kb1);
  } else {
    part_body<true, false>(srcP, bitmap, wcnts, lbufP, &lcntP, mA, l, h, qq, ka0, ka1);
    part_body<false, false>(srcM, bitmap, wcnts, lbufM, &lcntM, mB, l, h, qq, kb0, kb1);
  }

  __syncthreads();
  const unsigned int tP = lcntP, tM = lcntM;
  const unsigned int ccP = tP < SLOTS ? tP : SLOTS;
  const unsigned int ccM = tM < SLOTS ? tM : SLOTS;
  for (unsigned int i = threadIdx.x; i < ccP; i += 256)
    cand[(size_t)mA * CAP + j * SLOTS + i] = lbufP[i];
  for (unsigned int i = threadIdx.x; i < ccM; i += 256)
    cand[(size_t)mB * CAP + j * SLOTS + i] = lbufM[i];
  if (threadIdx.x == 0) {
    bcnt[mA * 64 + j] = tP;
    bcnt[mB * 64 + j] = tM;
  }
}

// block-level N = sum of the 256 per-unit counts.
__device__ __forceinline__ void reduce_N(const unsigned int* __restrict__ wcnts,
                                         int m, int tid, unsigned int* sN) {
  if (tid < 64) {
    const unsigned int* w = wcnts + m * 256;
    unsigned int v = w[tid] + w[tid + 64] + w[tid + 128] + w[tid + 192];
#pragma unroll
    for (int off = 32; off > 0; off >>= 1) v += __shfl_xor(v, off, 64);
    if (tid == 0) *sN = v;
  }
}

// ---------------------------------------------------------------------------
// K2: compact per-band slots -> radix-SELECT top-`need` set. Fallback exact
// bitmap rescan on overflow/shortfall (correctness unconditional).
// ---------------------------------------------------------------------------
__global__ __launch_bounds__(256) void select_kernel(
    const unsigned long long* __restrict__ bitmap,
    const unsigned int* __restrict__ wcnts,
    const unsigned long long* __restrict__ cand,
    const unsigned int* __restrict__ bcnt,
    uint32_t* __restrict__ pts, unsigned int* __restrict__ nsel) {
  const int m = blockIdx.x;
  const int tid = threadIdx.x;
  __shared__ unsigned long long buf[CAP];
  __shared__ unsigned int hist[256];
  __shared__ unsigned int scnt64[64];
  __shared__ unsigned int sbase[65];
  __shared__ unsigned int s_tot, s_cnt, s_b, s_rank, sN, s_ovf;

  reduce_N(wcnts, m, tid, &sN);
  if (tid < 64) scnt64[tid] = bcnt[m * 64 + tid];
  __syncthreads();
  const unsigned int N = sN;
  if (N == 0) { if (tid == 0) nsel[m] = 0; return; }
  const unsigned int need = N < NPTS ? N : NPTS;

  if (tid == 0) {
    unsigned int s = 0, ovf = 0;
    for (int i = 0; i < 64; ++i) {
      sbase[i] = s;
      unsigned int cg = scnt64[i];
      if (cg > SLOTS) ovf = 1;
      s += cg < SLOTS ? cg : SLOTS;
    }
    sbase[64] = s;
    s_ovf = ovf;
  }
  __syncthreads();

  unsigned int c;
  if (!s_ovf && sbase[64] >= need) {
    c = sbase[64];
    const int g = tid >> 2, j0 = tid & 3;  // 64 groups x 4 threads
    const unsigned int cg = scnt64[g] < SLOTS ? scnt64[g] : SLOTS;
    for (unsigned int i = j0; i < cg; i += 4)
      buf[sbase[g] + i] = cand[(size_t)m * CAP + g * SLOTS + i];
    __syncthreads();
  } else {
    // fallback: exact iterative rescan of the bitmap
    uint32_t k0, k1;
    map_key(m, k0, k1);
    const unsigned long long* __restrict__ wmap = bitmap + (size_t)m * NWORDS;
    unsigned int mt = 0, cnt = 0;
    double target = TARGET;
    for (int iter = 0; iter < 16; ++iter) {
      mt = ((double)N > target)
               ? (unsigned int)(8388608.0 * (1.0 - target / (double)N))
               : 0u;
      if (tid == 0) s_tot = 0;
      __syncthreads();
      unsigned int lc = 0;
      for (int w = tid; w < NWORDS; w += 256) {
        unsigned long long word = wmap[w];
        while (word) {
          int bpos = __builtin_ctzll(word);
          word &= word - 1;
          uint32_t p = ((uint32_t)w << 6) + (uint32_t)bpos;
          lc += (score23(k0, k1, p) >= mt) ? 1u : 0u;
        }
      }
      if (lc) atomicAdd(&s_tot, lc);
      __syncthreads();
      cnt = s_tot;
      __syncthreads();
      if (cnt >= need && cnt <= CAP) break;
      if (cnt < need) target *= 3.0; else target *= 0.5;
    }
    if (tid == 0) s_cnt = 0;
    __syncthreads();
    for (int w = tid; w < NWORDS; w += 256) {
      unsigned long long word = wmap[w];
      while (word) {
        int bpos = __builtin_ctzll(word);
        word &= word - 1;
        uint32_t p = ((uint32_t)w << 6) + (uint32_t)bpos;
        uint32_t sc = score23(k0, k1, p);
        if (sc >= mt) {
          unsigned int pos = atomicAdd(&s_cnt, 1u);
          if (pos < CAP)
            buf[pos] = ((unsigned long long)sc << 32) | (uint32_t)(~p);
        }
      }
    }
    __syncthreads();
    c = s_cnt < CAP ? s_cnt : CAP;
    __syncthreads();
  }

  unsigned long long T = 0ull;
  if (c > need) {
    unsigned int rank = need;
    unsigned long long prefix = 0ull;
    for (int sh = 48; sh >= 0; sh -= 8) {
      hist[tid] = 0;
      __syncthreads();
      for (unsigned int i = tid; i < c; i += 256) {
        unsigned long long k = buf[i];
        if ((k >> (sh + 8)) == (prefix >> (sh + 8)))
          atomicAdd(&hist[(unsigned int)(k >> sh) & 255u], 1u);
      }
      __syncthreads();
      if (tid < 64) {
        unsigned int h0 = hist[4 * tid], h1 = hist[4 * tid + 1];
        unsigned int h2 = hist[4 * tid + 2], h3 = hist[4 * tid + 3];
        unsigned int gsum = h0 + h1 + h2 + h3;
        unsigned int s = gsum;
#pragma unroll
        for (int off = 1; off < 64; off <<= 1) {
          unsigned int o = __shfl_down(s, off, 64);
          s += (tid + off < 64) ? o : 0u;
        }
        unsigned int above = s - gsum;  // strictly higher digits
        unsigned int S3 = above, S2 = S3 + h3, S1 = S2 + h2, S0 = S1 + h1;
        if (S3 < rank && rank <= S3 + h3) { s_b = 4 * tid + 3; s_rank = rank - S3; }
        if (S2 < rank && rank <= S2 + h2) { s_b = 4 * tid + 2; s_rank = rank - S2; }
        if (S1 < rank && rank <= S1 + h1) { s_b = 4 * tid + 1; s_rank = rank - S1; }
        if (S0 < rank && rank <= S0 + h0) { s_b = 4 * tid + 0; s_rank = rank - S0; }
      }
      __syncthreads();
      prefix |= ((unsigned long long)s_b) << sh;
      rank = s_rank;
    }
    T = prefix;  // exact need-th largest key
  }

  if (tid == 0) s_cnt = 0;
  __syncthreads();
  for (unsigned int i = tid; i < c; i += 256) {
    unsigned long long k = buf[i];
    if (k >= T) {
      unsigned int pos = atomicAdd(&s_cnt, 1u);
      if (pos < NPTS) {
        uint32_t p = ~(uint32_t)k;
        pts[(size_t)m * NPTS + pos] = ((p >> 9) << 16) | (p & 511u);
      }
    }
  }
  __syncthreads();
  if (tid == 0) nsel[m] = s_cnt < need ? s_cnt : need;
}

// ---------------------------------------------------------------------------
// K3: Prim MST + fused finalize. r6: payload-carrying DPP reduction.
//  - r4/r5 lesson: lone-wave cost ~ chain instruction count; LDS-crossbar
//    ops (~60-100cy) and >2 readlanes are the expensive primitives.
//  - carry (key, packed coords) through local min tree + 6 DPP hops
//    (r3-validated ctrl constants); lane 63 ends with BOTH min key and
//    its owner's coords -> no j/ko/lo fetch path at all.
//  - exactly 2 readlanes (best, pj), issued back-to-back.
//  - owner invalidation by unique-key equality (key[k]==best).
//  - px/py/idc precomputed outside the loop (restores r3's form).
// Integer math identical (min order-invariant, unique keys) -> absmax 0.
// ---------------------------------------------------------------------------
__global__ __launch_bounds__(128, 1) void mst_kernel(
    const uint32_t* __restrict__ pts, const unsigned int* __restrict__ nsel,
    float* __restrict__ out) {
  const int wv = threadIdx.x >> 6;  // 0 = pred, 1 = mask
  const int m = blockIdx.x * 2 + wv;
  const int l = threadIdx.x & 63;
  const int n = (int)nsel[m];
  __shared__ float stp[2];

  uint32_t utp = 0;
  if (n > 1) {
    uint32_t pk[5], key[5], idc[5];
    int px[5], py[5];
#pragma unroll
    for (int k = 0; k < 5; ++k) {
      int id = k * 64 + l;
      pk[k] = (id < n) ? pts[(size_t)m * NPTS + id] : 0u;
      px[k] = (int)(pk[k] >> 16);
      py[k] = (int)(pk[k] & 0xFFFFu);
      idc[k] = (uint32_t)id;
    }
    const uint32_t p0 = (uint32_t)__builtin_amdgcn_readlane((int)pk[0], 0);
    const int x0 = (int)(p0 >> 16), y0 = (int)(p0 & 0xFFFFu);
#pragma unroll
    for (int k = 0; k < 5; ++k) {
      int id = k * 64 + l;
      if (id > 0 && id < n) {
        int dx = px[k] - x0, dy = py[k] - y0;
        key[k] = ((uint32_t)(__mul24(dx, dx) + __mul24(dy, dy)) << 9) |
                 idc[k];
      } else {
        key[k] = 0xFFFFFFFFu;
      }
    }

    for (int it = 0; it < n - 1; ++it) {
      // local argmin tree (depth 3) with coordinate payload.
      uint32_t k01 = umin32(key[0], key[1]);
      uint32_t p01 = (key[1] < key[0]) ? pk[1] : pk[0];
      uint32_t k23 = umin32(key[2], key[3]);
      uint32_t p23 = (key[3] < key[2]) ? pk[3] : pk[2];
      uint32_t k234 = umin32(k23, key[4]);
      uint32_t p234 = (key[4] < k23) ? pk[4] : p23;
      uint32_t bk = umin32(k01, k234);
      uint32_t bp = (k234 < k01) ? p234 : p01;
      // 6 DPP hops, payload-carrying (r3-validated ctrl sequence).
#define HOP(CTRL)                                                   \
      {                                                             \
        uint32_t kd = dpp_mov_u32<CTRL>(bk);                        \
        uint32_t pd = dpp_mov_u32<CTRL>(bp);                        \
        bool cc = kd < bk;                                          \
        bk = umin32(bk, kd);                                        \
        bp = cc ? pd : bp;                                          \
      }
      HOP(0x111)  // row_shr:1
      HOP(0x112)  // row_shr:2
      HOP(0x114)  // row_shr:4
      HOP(0x118)  // row_shr:8
      HOP(0x142)  // row_bcast:15
      HOP(0x143)  // row_bcast:31
#undef HOP
      // lane 63 holds min key AND its owner's packed coords.
      const uint32_t best = (uint32_t)__builtin_amdgcn_readlane((int)bk, 63);
      const uint32_t pj = (uint32_t)__builtin_amdgcn_readlane((int)bp, 63);
      utp += best >> 9;  // exact: sum < 2^31
      const int jx = (int)(pj >> 16), jy = (int)(pj & 0xFFFFu);
#pragma unroll
      for (int k = 0; k < 5; ++k) {
        int dx = px[k] - jx, dy = py[k] - jy;
        uint32_t nk = ((uint32_t)(__mul24(dx, dx) + __mul24(dy, dy)) << 9) |
                      idc[k];
        uint32_t upd =
            (key[k] == 0xFFFFFFFFu) ? 0xFFFFFFFFu : umin32(key[k], nk);
        key[k] = (key[k] == best) ? 0xFFFFFFFFu : upd;
      }
    }
  }
  if (l == 0) stp[wv] = (float)utp;
  __syncthreads();
  if (threadIdx.x == 0)
    atomicAdd(out, 1e-5f * fabsf(stp[1] - stp[0]) / 32.f);
}

// ---------------------------------------------------------------------------
extern "C" void kernel_launch(void* const* d_in, const int* in_sizes, int n_in,
                              void* d_out, int out_size, void* d_ws,
                              size_t ws_size, hipStream_t stream) {
  const float* mo = (const float*)d_in[0];
  const float* lb = (const float*)d_in[1];
  float* out = (float*)d_out;
  char* ws = (char*)d_ws;

  // ws layout (~3.30 MB):
  unsigned long long* bitmap = (unsigned long long*)ws;            // 2 MB
  unsigned long long* cand = (unsigned long long*)(ws + 2097152);  // 1 MB
  unsigned int* wcnts = (unsigned int*)(ws + 3145728);             // 64 KB
  unsigned int* bcnt  = (unsigned int*)(ws + 3211264);             // 16 KB
  unsigned int* nsel  = (unsigned int*)(ws + 3227648);             // 256 B
  uint32_t* pts       = (uint32_t*)(ws + 3227904);                 // 75 KB

  edge_collect_kernel<<<2048, 256, 0, stream>>>(mo, lb, bitmap, wcnts,
                                                cand, bcnt, out);
  select_kernel<<<NMAPS, 256, 0, stream>>>(bitmap, wcnts, cand, bcnt, pts,
                                           nsel);
  mst_kernel<<<32, 128, 0, stream>>>(pts, nsel, out);
}

// Round 8
// 216.035 us; speedup vs baseline: 1.0843x; 1.0167x over previous
//
#include <hip/hip_runtime.h>
#include <cstdint>
#include <cstddef>

#define NPIX (512 * 512)
#define NMAPS 64
#define NPTS 300
#define CAP 2048           // per-map candidate region (64 bands x 32 slots)
#define SLOTS 32           // per-band-per-map candidate slots (E~9.7, 7 sigma)
#define LBUFSZ 64          // LDS staging per part
#define NWORDS 4096        // 262144 bits / 64
#define TARGET 700.0       // fallback rescan target
// Fixed keep-rate 20000/2^23: E~620 survivors/map.
// Compare raw threefry bits against MT<<9 (exactly equiv to score>=MT).
#define MT_BITS 0xFF63C000u  // (8388608-20000)<<9

__device__ __forceinline__ uint32_t umin32(uint32_t a, uint32_t b) {
  return a < b ? a : b;
}

// Portable rotate; r is always a compile-time constant in [6,29], clang
// lowers this to a single v_alignbit_b32 on gfx950.
__device__ __forceinline__ uint32_t rotl32(uint32_t x, int r) {
  return (x << r) | (x >> (32 - r));
}

// ---------------------------------------------------------------------------
// Threefry-2x32, 20 rounds (exactly JAX's formulation).
// Scalar version (K2 fallback + key derivation).
// ---------------------------------------------------------------------------
__device__ __forceinline__ void tf2x32(uint32_t k0, uint32_t k1,
                                       uint32_t x0, uint32_t x1,
                                       uint32_t& o0, uint32_t& o1) {
  uint32_t ks2 = k0 ^ k1 ^ 0x1BD11BDAu;
#define TFR(r) { x0 += x1; x1 = rotl32(x1, r); x1 ^= x0; }
  x0 += k0; x1 += k1;
  TFR(13) TFR(15) TFR(26) TFR(6)
  x0 += k1; x1 += ks2 + 1u;
  TFR(17) TFR(29) TFR(16) TFR(24)
  x0 += ks2; x1 += k0 + 2u;
  TFR(13) TFR(15) TFR(26) TFR(6)
  x0 += k0; x1 += k1 + 3u;
  TFR(17) TFR(29) TFR(16) TFR(24)
  x0 += k1; x1 += ks2 + 4u;
  TFR(13) TFR(15) TFR(26) TFR(6)
  x0 += ks2; x1 += k0 + 5u;
#undef TFR
  o0 = x0; o1 = x1;
}

// 4-pixel batched threefry: 4 manually interleaved chains (counter pb..pb+3).
// Guarantees 4-way ILP on the serial add->rotl->xor chain.
__device__ __forceinline__ void tf4(uint32_t k0, uint32_t k1, uint32_t pb,
                                    uint32_t& z0, uint32_t& z1, uint32_t& z2,
                                    uint32_t& z3) {
  const uint32_t ks2 = k0 ^ k1 ^ 0x1BD11BDAu;
  const uint32_t s = pb + k1;
  uint32_t a0 = k0, a1 = s;
  uint32_t b0 = k0, b1 = s + 1u;
  uint32_t c0 = k0, c1 = s + 2u;
  uint32_t d0 = k0, d1 = s + 3u;
#define R4(r)                                                         \
  a0 += a1; b0 += b1; c0 += c1; d0 += d1;                             \
  a1 = rotl32(a1, r); b1 = rotl32(b1, r);                             \
  c1 = rotl32(c1, r); d1 = rotl32(d1, r);                             \
  a1 ^= a0; b1 ^= b0; c1 ^= c0; d1 ^= d0;
#define K4(ka, kb)                                                    \
  a0 += (ka); b0 += (ka); c0 += (ka); d0 += (ka);                     \
  a1 += (kb); b1 += (kb); c1 += (kb); d1 += (kb);
  R4(13) R4(15) R4(26) R4(6)  K4(k1, ks2 + 1u)
  R4(17) R4(29) R4(16) R4(24) K4(ks2, k0 + 2u)
  R4(13) R4(15) R4(26) R4(6)  K4(k0, k1 + 3u)
  R4(17) R4(29) R4(16) R4(24) K4(k1, ks2 + 4u)
  R4(13) R4(15) R4(26) R4(6)  K4(ks2, k0 + 5u)
#undef R4
#undef K4
  z0 = a0 ^ a1; z1 = b0 ^ b1; z2 = c0 ^ c1; z3 = d0 ^ d1;
}

__device__ __forceinline__ uint32_t score23(uint32_t k0, uint32_t k1, uint32_t p) {
  uint32_t a, b;
  tf2x32(k0, k1, 0u, p, a, b);
  return (a ^ b) >> 9;
}

__device__ __forceinline__ void map_key(int m, uint32_t& k0, uint32_t& k1) {
  tf2x32(0u, 42u, 0u, (uint32_t)m, k0, k1);  // split(key(42),64)[m]
}

// DPP helper (validated ctrl constants; CTRL must be an ICE -> template).
// VALIDATED FAMILY ONLY: row_shl:N (0x100+N), row_shr:N (0x110+N),
// row_bcast:15/31 (0x142/0x143). CDNA has NO wave_shl/wave_shr (r7 lesson).
template <int CTRL>
__device__ __forceinline__ uint32_t dpp_mov_u32(uint32_t x) {
  return (uint32_t)__builtin_amdgcn_update_dpp((int)x, (int)x, CTRL, 0xF, 0xF,
                                               false);
}

// DPP with old=0: invalid source lanes contribute 0 (for OR-reduce).
template <int CTRL>
__device__ __forceinline__ uint32_t dpp_or0(uint32_t x) {
  return (uint32_t)__builtin_amdgcn_update_dpp(0, (int)x, CTRL, 0xF, 0xF,
                                               false);
}

// float DPP mov (bitcast through u32).
template <int CTRL>
__device__ __forceinline__ float dpp_mov_f32(float x) {
  return __uint_as_float(dpp_mov_u32<CTRL>(__float_as_uint(x)));
}

// wave-64 u32 min reduction (HW-validated, absmax 0 across rounds).
__device__ __forceinline__ uint32_t wave_min_u32_bcast(uint32_t v) {
  v = umin32(v, dpp_mov_u32<0x111>(v));  // row_shr:1
  v = umin32(v, dpp_mov_u32<0x112>(v));  // row_shr:2
  v = umin32(v, dpp_mov_u32<0x114>(v));  // row_shr:4
  v = umin32(v, dpp_mov_u32<0x118>(v));  // row_shr:8
  v = umin32(v, dpp_mov_u32<0x142>(v));  // row_bcast:15
  v = umin32(v, dpp_mov_u32<0x143>(v));  // row_bcast:31
  return (uint32_t)__builtin_amdgcn_readlane((int)v, 63);
}

// ---------------------------------------------------------------------------
// K1 loads: 4 contiguous columns per lane via float4; sigmoid at load.
// ---------------------------------------------------------------------------
template <bool PRED, bool YIN>
__device__ __forceinline__ float4 ld4row(const float* __restrict__ src,
                                         int row, int X0) {
  if constexpr (!YIN) {
    if ((unsigned)row >= 512u) return make_float4(0.f, 0.f, 0.f, 0.f);
  }
  float4 v = *reinterpret_cast<const float4*>(src + (size_t)row * 512 + X0);
  if constexpr (PRED) {
    v.x = 1.f / (1.f + __expf(-v.x));
    v.y = 1.f / (1.f + __expf(-v.y));
    v.z = 1.f / (1.f + __expf(-v.z));
    v.w = 1.f / (1.f + __expf(-v.w));
  }
  return v;
}

template <bool PRED, bool YIN>
__device__ __forceinline__ float ldhrow(const float* __restrict__ src,
                                        int row, int hx, bool hact) {
  if (!hact) return 0.f;  // inactive/OOB lanes: raw 0 (zero-pad semantics)
  if constexpr (!YIN) {
    if ((unsigned)row >= 512u) return 0.f;
  }
  float t = src[(size_t)row * 512 + hx];
  if constexpr (PRED) t = 1.f / (1.f + __expf(-t));
  return t;
}

__device__ __forceinline__ void push_surv(unsigned long long* lbuf,
                                          unsigned int* lcnt, uint32_t x,
                                          uint32_t p) {
  unsigned int pos = atomicAdd(lcnt, 1u);
  if (pos < LBUFSZ)
    lbuf[pos] = ((unsigned long long)(x >> 9) << 32) | (uint32_t)(~p);
}

// ---------------------------------------------------------------------------
// K1 part body: 4 rows x 256 cols (half width) of ONE map. Each wave runs
// this twice (pred part + mask part) -> perfect pred/mask load balance.
// Neighbor exchange via DPP row_shr:1 / row_shl:1 (validated family,
// 1 VALU op, no LDS/lgkmcnt). The 8 row-boundary lanes (lr==0/15) take
// their neighbor value from a directly-loaded halo column instead:
//   lr==0  -> col X0-1  (lane 0,h=0: OOB -> 0, matches zero-pad)
//   lr==15 -> col X0+4  (lane 63,h=1: OOB -> 0)
// Values delivered per lane are bit-identical to the old __shfl path.
// ---------------------------------------------------------------------------
template <bool PRED, bool YIN>
__device__ __forceinline__ void part_body(
    const float* __restrict__ src, unsigned long long* __restrict__ bitmap,
    unsigned int* __restrict__ wcnts, unsigned long long* lbuf,
    unsigned int* lcnt, int m, int l, int h, int qq, uint32_t k0,
    uint32_t k1) {
  const int y0 = qq * 4;
  const int X0 = h * 256 + l * 4;
  const int lr = l & 15;
  const int hx = (lr == 0) ? (X0 - 1) : (X0 + 4);  // used only by lr==0/15
  const bool hact = ((lr == 0) || (lr == 15)) && ((unsigned)hx < 512u);

  float4 fA = ld4row<PRED, YIN>(src, y0 - 1, X0);
  float4 fB = ld4row<PRED, YIN>(src, y0 + 0, X0);
  float4 fC = ld4row<PRED, YIN>(src, y0 + 1, X0);
  float4 fD = ld4row<PRED, YIN>(src, y0 + 2, X0);
  float sA = ldhrow<PRED, YIN>(src, y0 - 1, hx, hact);
  float sB = ldhrow<PRED, YIN>(src, y0 + 0, hx, hact);
  float sC = ldhrow<PRED, YIN>(src, y0 + 1, hx, hact);
  float sD = ldhrow<PRED, YIN>(src, y0 + 2, hx, hact);

  unsigned int cnt = 0;
  unsigned long long* __restrict__ bm2 =
      bitmap + (size_t)m * NWORDS + (size_t)y0 * 8 + (h * 4 + (l >> 4));
  uint32_t pbase = (uint32_t)(y0 * 512 + X0);

#define ROWQ(RA, RB, RC, SA, SB, SC, II)                                      \
  do {                                                                        \
    float t0 = RA.x + 2.f * RB.x + RC.x, t1 = RA.y + 2.f * RB.y + RC.y;       \
    float t2 = RA.z + 2.f * RB.z + RC.z, t3 = RA.w + 2.f * RB.w + RC.w;       \
    float u0 = RC.x - RA.x, u1 = RC.y - RA.y;                                 \
    float u2 = RC.z - RA.z, u3 = RC.w - RA.w;                                 \
    float th = SA + 2.f * SB + SC, uh = SC - SA;                              \
    float tU = dpp_mov_f32<0x111>(t3);  /* row_shr:1: lane l <- l-1 */        \
    float uU = dpp_mov_f32<0x111>(u3);                                        \
    float tD = dpp_mov_f32<0x101>(t0);  /* row_shl:1: lane l <- l+1 */        \
    float uD = dpp_mov_f32<0x101>(u0);                                        \
    if (lr == 0) { tU = th; uU = uh; }                                        \
    if (lr == 15) { tD = th; uD = uh; }                                       \
    float ex0 = t1 - tU, ex1 = t2 - t0, ex2 = t3 - t1, ex3 = tD - t2;         \
    float ey0 = uU + 2.f * u0 + u1, ey1 = u0 + 2.f * u1 + u2;                 \
    float ey2 = u1 + 2.f * u2 + u3, ey3 = u2 + 2.f * u3 + uD;                 \
    uint32_t nib = (ex0 * ex0 + ey0 * ey0 > 0.25f ? 1u : 0u) |                \
                   (ex1 * ex1 + ey1 * ey1 > 0.25f ? 2u : 0u) |                \
                   (ex2 * ex2 + ey2 * ey2 > 0.25f ? 4u : 0u) |                \
                   (ex3 * ex3 + ey3 * ey3 > 0.25f ? 8u : 0u);                 \
    uint32_t z0, z1, z2, z3;                                                  \
    tf4(k0, k1, pbase, z0, z1, z2, z3);                                       \
    uint32_t qm = (z0 >= MT_BITS ? 1u : 0u) | (z1 >= MT_BITS ? 2u : 0u) |     \
                  (z2 >= MT_BITS ? 4u : 0u) | (z3 >= MT_BITS ? 8u : 0u);      \
    uint32_t sv = nib & qm;                                                   \
    if (sv) {                                                                 \
      if (sv & 1u) push_surv(lbuf, lcnt, z0, pbase);                          \
      if (sv & 2u) push_surv(lbuf, lcnt, z1, pbase + 1u);                     \
      if (sv & 4u) push_surv(lbuf, lcnt, z2, pbase + 2u);                     \
      if (sv & 8u) push_surv(lbuf, lcnt, z3, pbase + 3u);                     \
    }                                                                         \
    unsigned long long full = (unsigned long long)nib << (4 * lr);            \
    uint32_t wlo = (uint32_t)full, whi = (uint32_t)(full >> 32);              \
    wlo |= dpp_or0<0x111>(wlo); whi |= dpp_or0<0x111>(whi);                   \
    wlo |= dpp_or0<0x112>(wlo); whi |= dpp_or0<0x112>(whi);                   \
    wlo |= dpp_or0<0x114>(wlo); whi |= dpp_or0<0x114>(whi);                   \
    wlo |= dpp_or0<0x118>(wlo); whi |= dpp_or0<0x118>(whi);                   \
    if (lr == 15) {                                                           \
      unsigned long long word = ((unsigned long long)whi << 32) | wlo;        \
      bm2[(II) * 8] = word;                                                   \
      cnt += (unsigned int)__popcll(word);                                    \
    }                                                                         \
    pbase += 512u;                                                            \
  } while (0)

  ROWQ(fA, fB, fC, sA, sB, sC, 0);
  fA = ld4row<PRED, YIN>(src, y0 + 3, X0);
  sA = ldhrow<PRED, YIN>(src, y0 + 3, hx, hact);
  ROWQ(fB, fC, fD, sB, sC, sD, 1);
  fB = ld4row<PRED, YIN>(src, y0 + 4, X0);
  sB = ldhrow<PRED, YIN>(src, y0 + 4, hx, hact);
  ROWQ(fC, fD, fA, sC, sD, sA, 2);
  ROWQ(fD, fA, fB, sD, sA, sB, 3);
#undef ROWQ

  // unit total = sum of the 4 tail-lane partials (lanes 15/31/47/63).
  cnt += __shfl_xor(cnt, 16);
  cnt += __shfl_xor(cnt, 32);
  if (l == 15) wcnts[m * 256 + 2 * qq + h] = cnt;
}

// ---------------------------------------------------------------------------
// K1: fused Sobel+threefry+collect, pred/mask balanced. 2048 blocks (1D):
// block b -> sample s = b>>6, band j = b&63 (rows [8j, 8j+8)). Each of the
// 4 waves: h = v&1, qq = 2j + (v>>1); does 4 pred rows THEN 4 mask rows.
// Every block has identical cost -> no pred-tail.
// ---------------------------------------------------------------------------
__global__ __launch_bounds__(256) void edge_collect_kernel(
    const float* __restrict__ mo, const float* __restrict__ lb,
    unsigned long long* __restrict__ bitmap, unsigned int* __restrict__ wcnts,
    unsigned long long* __restrict__ cand, unsigned int* __restrict__ bcnt,
    float* __restrict__ out) {
  const int b = blockIdx.x;
  const int s = b >> 6;        // sample [0,32)
  const int j = b & 63;        // 8-row band [0,64)
  const int v = threadIdx.x >> 6;
  const int l = threadIdx.x & 63;
  const int h = v & 1;
  const int qq = 2 * j + (v >> 1);  // row-quad [0,128)
  const int mA = 2 * s;        // pred map (model_output)
  const int mB = 2 * s + 1;    // mask map (labels)
  const float* __restrict__ srcP = mo + (size_t)s * NPIX;
  const float* __restrict__ srcM = lb + (size_t)s * NPIX;

  if (b == 0 && threadIdx.x == 0) out[0] = 0.f;

  __shared__ unsigned long long lbufP[LBUFSZ], lbufM[LBUFSZ];
  __shared__ unsigned int lcntP, lcntM;
  if (threadIdx.x == 0) { lcntP = 0; lcntM = 0; }
  __syncthreads();

  uint32_t ka0, ka1, kb0, kb1;
  map_key(mA, ka0, ka1);
  map_key(mB, kb0, kb1);
  ka0 = (uint32_t)__builtin_amdgcn_readfirstlane((int)ka0);
  ka1 = (uint32_t)__builtin_amdgcn_readfirstlane((int)ka1);
  kb0 = (uint32_t)__builtin_amdgcn_readfirstlane((int)kb0);
  kb1 = (uint32_t)__builtin_amdgcn_readfirstlane((int)kb1);

  const bool yin = (qq != 0) && (qq != 127);
  if (yin) {
    part_body<true, true>(srcP, bitmap, wcnts, lbufP, &lcntP, mA, l, h, qq, ka0, ka1);
    part_body<false, true>(srcM, bitmap, wcnts, lbufM, &lcntM, mB, l, h, qq, kb0, kb1);
  } else {
    part_body<true, false>(srcP, bitmap, wcnts, lbufP, &lcntP, mA, l, h, qq, ka0, ka1);
    part_body<false, false>(srcM, bitmap, wcnts, lbufM, &lcntM, mB, l, h, qq, kb0, kb1);
  }

  __syncthreads();
  const unsigned int tP = lcntP, tM = lcntM;
  const unsigned int ccP = tP < SLOTS ? tP : SLOTS;
  const unsigned int ccM = tM < SLOTS ? tM : SLOTS;
  for (unsigned int i = threadIdx.x; i < ccP; i += 256)
    cand[(size_t)mA * CAP + j * SLOTS + i] = lbufP[i];
  for (unsigned int i = threadIdx.x; i < ccM; i += 256)
    cand[(size_t)mB * CAP + j * SLOTS + i] = lbufM[i];
  if (threadIdx.x == 0) {
    bcnt[mA * 64 + j] = tP;
    bcnt[mB * 64 + j] = tM;
  }
}

// block-level N = sum of the 256 per-unit counts.
__device__ __forceinline__ void reduce_N(const unsigned int* __restrict__ wcnts,
                                         int m, int tid, unsigned int* sN) {
  if (tid < 64) {
    const unsigned int* w = wcnts + m * 256;
    unsigned int v = w[tid] + w[tid + 64] + w[tid + 128] + w[tid + 192];
#pragma unroll
    for (int off = 32; off > 0; off >>= 1) v += __shfl_xor(v, off, 64);
    if (tid == 0) *sN = v;
  }
}

// ---------------------------------------------------------------------------
// K2: compact per-band slots -> radix-SELECT top-`need` set. Fallback exact
// bitmap rescan on overflow/shortfall (correctness unconditional).
// ---------------------------------------------------------------------------
__global__ __launch_bounds__(256) void select_kernel(
    const unsigned long long* __restrict__ bitmap,
    const unsigned int* __restrict__ wcnts,
    const unsigned long long* __restrict__ cand,
    const unsigned int* __restrict__ bcnt,
    uint32_t* __restrict__ pts, unsigned int* __restrict__ nsel) {
  const int m = blockIdx.x;
  const int tid = threadIdx.x;
  __shared__ unsigned long long buf[CAP];
  __shared__ unsigned int hist[256];
  __shared__ unsigned int scnt64[64];
  __shared__ unsigned int sbase[65];
  __shared__ unsigned int s_tot, s_cnt, s_b, s_rank, sN, s_ovf;

  reduce_N(wcnts, m, tid, &sN);
  if (tid < 64) scnt64[tid] = bcnt[m * 64 + tid];
  __syncthreads();
  const unsigned int N = sN;
  if (N == 0) { if (tid == 0) nsel[m] = 0; return; }
  const unsigned int need = N < NPTS ? N : NPTS;

  if (tid == 0) {
    unsigned int s = 0, ovf = 0;
    for (int i = 0; i < 64; ++i) {
      sbase[i] = s;
      unsigned int cg = scnt64[i];
      if (cg > SLOTS) ovf = 1;
      s += cg < SLOTS ? cg : SLOTS;
    }
    sbase[64] = s;
    s_ovf = ovf;
  }
  __syncthreads();

  unsigned int c;
  if (!s_ovf && sbase[64] >= need) {
    c = sbase[64];
    const int g = tid >> 2, j0 = tid & 3;  // 64 groups x 4 threads
    const unsigned int cg = scnt64[g] < SLOTS ? scnt64[g] : SLOTS;
    for (unsigned int i = j0; i < cg; i += 4)
      buf[sbase[g] + i] = cand[(size_t)m * CAP + g * SLOTS + i];
    __syncthreads();
  } else {
    // fallback: exact iterative rescan of the bitmap
    uint32_t k0, k1;
    map_key(m, k0, k1);
    const unsigned long long* __restrict__ wmap = bitmap + (size_t)m * NWORDS;
    unsigned int mt = 0, cnt = 0;
    double target = TARGET;
    for (int iter = 0; iter < 16; ++iter) {
      mt = ((double)N > target)
               ? (unsigned int)(8388608.0 * (1.0 - target / (double)N))
               : 0u;
      if (tid == 0) s_tot = 0;
      __syncthreads();
      unsigned int lc = 0;
      for (int w = tid; w < NWORDS; w += 256) {
        unsigned long long word = wmap[w];
        while (word) {
          int bpos = __builtin_ctzll(word);
          word &= word - 1;
          uint32_t p = ((uint32_t)w << 6) + (uint32_t)bpos;
          lc += (score23(k0, k1, p) >= mt) ? 1u : 0u;
        }
      }
      if (lc) atomicAdd(&s_tot, lc);
      __syncthreads();
      cnt = s_tot;
      __syncthreads();
      if (cnt >= need && cnt <= CAP) break;
      if (cnt < need) target *= 3.0; else target *= 0.5;
    }
    if (tid == 0) s_cnt = 0;
    __syncthreads();
    for (int w = tid; w < NWORDS; w += 256) {
      unsigned long long word = wmap[w];
      while (word) {
        int bpos = __builtin_ctzll(word);
        word &= word - 1;
        uint32_t p = ((uint32_t)w << 6) + (uint32_t)bpos;
        uint32_t sc = score23(k0, k1, p);
        if (sc >= mt) {
          unsigned int pos = atomicAdd(&s_cnt, 1u);
          if (pos < CAP)
            buf[pos] = ((unsigned long long)sc << 32) | (uint32_t)(~p);
        }
      }
    }
    __syncthreads();
    c = s_cnt < CAP ? s_cnt : CAP;
    __syncthreads();
  }

  unsigned long long T = 0ull;
  if (c > need) {
    unsigned int rank = need;
    unsigned long long prefix = 0ull;
    for (int sh = 48; sh >= 0; sh -= 8) {
      hist[tid] = 0;
      __syncthreads();
      for (unsigned int i = tid; i < c; i += 256) {
        unsigned long long k = buf[i];
        if ((k >> (sh + 8)) == (prefix >> (sh + 8)))
          atomicAdd(&hist[(unsigned int)(k >> sh) & 255u], 1u);
      }
      __syncthreads();
      if (tid < 64) {
        unsigned int h0 = hist[4 * tid], h1 = hist[4 * tid + 1];
        unsigned int h2 = hist[4 * tid + 2], h3 = hist[4 * tid + 3];
        unsigned int gsum = h0 + h1 + h2 + h3;
        unsigned int s = gsum;
#pragma unroll
        for (int off = 1; off < 64; off <<= 1) {
          unsigned int o = __shfl_down(s, off, 64);
          s += (tid + off < 64) ? o : 0u;
        }
        unsigned int above = s - gsum;  // strictly higher digits
        unsigned int S3 = above, S2 = S3 + h3, S1 = S2 + h2, S0 = S1 + h1;
        if (S3 < rank && rank <= S3 + h3) { s_b = 4 * tid + 3; s_rank = rank - S3; }
        if (S2 < rank && rank <= S2 + h2) { s_b = 4 * tid + 2; s_rank = rank - S2; }
        if (S1 < rank && rank <= S1 + h1) { s_b = 4 * tid + 1; s_rank = rank - S1; }
        if (S0 < rank && rank <= S0 + h0) { s_b = 4 * tid + 0; s_rank = rank - S0; }
      }
      __syncthreads();
      prefix |= ((unsigned long long)s_b) << sh;
      rank = s_rank;
    }
    T = prefix;  // exact need-th largest key
  }

  if (tid == 0) s_cnt = 0;
  __syncthreads();
  for (unsigned int i = tid; i < c; i += 256) {
    unsigned long long k = buf[i];
    if (k >= T) {
      unsigned int pos = atomicAdd(&s_cnt, 1u);
      if (pos < NPTS) {
        uint32_t p = ~(uint32_t)k;
        pts[(size_t)m * NPTS + pos] = ((p >> 9) << 16) | (p & 511u);
      }
    }
  }
  __syncthreads();
  if (tid == 0) nsel[m] = s_cnt < need ? s_cnt : need;
}

// ---------------------------------------------------------------------------
// K3: Prim MST + fused finalize — r3-proven 77 µs version, verbatim
// (r4/r5/r6 restructurings all measured slower: 95.5/88/87).
// ---------------------------------------------------------------------------
__global__ __launch_bounds__(128, 1) void mst_kernel(
    const uint32_t* __restrict__ pts, const unsigned int* __restrict__ nsel,
    float* __restrict__ out) {
  const int wv = threadIdx.x >> 6;  // 0 = pred, 1 = mask
  const int m = blockIdx.x * 2 + wv;
  const int l = threadIdx.x & 63;
  const int n = (int)nsel[m];
  __shared__ float stp[2];

  unsigned int utp = 0;
  if (n > 1) {
    uint32_t pk[5], key[5];
    int px[5], py[5];
#pragma unroll
    for (int k = 0; k < 5; ++k) {
      int id = k * 64 + l;
      pk[k] = (id < n) ? pts[(size_t)m * NPTS + id] : 0u;
    }
    const uint32_t p0 = (uint32_t)__builtin_amdgcn_readlane((int)pk[0], 0);
    const int x0 = (int)(p0 >> 16), y0 = (int)(p0 & 0xFFFFu);
#pragma unroll
    for (int k = 0; k < 5; ++k) {
      int id = k * 64 + l;
      px[k] = (int)(pk[k] >> 16);
      py[k] = (int)(pk[k] & 0xFFFFu);
      if (id > 0 && id < n) {
        int dx = px[k] - x0, dy = py[k] - y0;
        key[k] = ((uint32_t)(__mul24(dx, dx) + __mul24(dy, dy)) << 9) |
                 (uint32_t)id;
      } else {
        key[k] = 0xFFFFFFFFu;
      }
    }

    for (int it = 0; it < n - 1; ++it) {
      uint32_t best = umin32(umin32(umin32(key[0], key[1]),
                                    umin32(key[2], key[3])), key[4]);
      best = wave_min_u32_bcast(best);
      utp += best >> 9;  // exact: sum < 2^31
      const int j = (int)(best & 511u);
      const int ko = j >> 6, lo = j & 63;
      uint32_t cp = pk[0];
#pragma unroll
      for (int k = 1; k < 5; ++k) cp = (ko == k) ? pk[k] : cp;
      const uint32_t pj = (uint32_t)__builtin_amdgcn_readlane((int)cp, lo);
      const int jx = (int)(pj >> 16), jy = (int)(pj & 0xFFFFu);
#pragma unroll
      for (int k = 0; k < 5; ++k) {
        int dx = px[k] - jx, dy = py[k] - jy;
        uint32_t nk = ((uint32_t)(__mul24(dx, dx) + __mul24(dy, dy)) << 9) |
                      (uint32_t)(k * 64 + l);
        uint32_t upd =
            (key[k] == 0xFFFFFFFFu) ? 0xFFFFFFFFu : umin32(key[k], nk);
        key[k] = (k == ko && l == lo) ? 0xFFFFFFFFu : upd;
      }
    }
  }
  if (l == 0) stp[wv] = (float)utp;
  __syncthreads();
  if (threadIdx.x == 0)
    atomicAdd(out, 1e-5f * fabsf(stp[1] - stp[0]) / 32.f);
}

// ---------------------------------------------------------------------------
extern "C" void kernel_launch(void* const* d_in, const int* in_sizes, int n_in,
                              void* d_out, int out_size, void* d_ws,
                              size_t ws_size, hipStream_t stream) {
  const float* mo = (const float*)d_in[0];
  const float* lb = (const float*)d_in[1];
  float* out = (float*)d_out;
  char* ws = (char*)d_ws;

  // ws layout (~3.30 MB):
  unsigned long long* bitmap = (unsigned long long*)ws;            // 2 MB
  unsigned long long* cand = (unsigned long long*)(ws + 2097152);  // 1 MB
  unsigned int* wcnts = (unsigned int*)(ws + 3145728);             // 64 KB
  unsigned int* bcnt  = (unsigned int*)(ws + 3211264);             // 16 KB
  unsigned int* nsel  = (unsigned int*)(ws + 3227648);             // 256 B
  uint32_t* pts       = (uint32_t*)(ws + 3227904);                 // 75 KB

  edge_collect_kernel<<<2048, 256, 0, stream>>>(mo, lb, bitmap, wcnts,
                                                cand, bcnt, out);
  select_kernel<<<NMAPS, 256, 0, stream>>>(bitmap, wcnts, cand, bcnt, pts,
                                           nsel);
  mst_kernel<<<32, 128, 0, stream>>>(pts, nsel, out);
}